// Round 5
// baseline (3194.741 us; speedup 1.0000x reference)
//
#include <hip/hip_runtime.h>
#include <math.h>

#define EPSV 1e-5f

__device__ __forceinline__ float wsum(float v){
  #pragma unroll
  for(int m=32;m;m>>=1) v += __shfl_xor(v,m);
  return v;
}
__device__ __forceinline__ float wmax_(float v){
  #pragma unroll
  for(int m=32;m;m>>=1) v = fmaxf(v,__shfl_xor(v,m));
  return v;
}

// ------------------------------------------------------------------
// conv1 (3->20, 5x5, VALID) + bias + relu + 2x2 maxpool -> A[np][20][54][54]
// grid (24 = rowt*4 + colh*2 + och, chunk). 256 thr = 4 waves.
// Each block: 10 output channels x 9x27 output tile. Weights scalar-loaded
// (uniform addr) -> VALU does only FMAs + LDS window reads.
// ------------------------------------------------------------------
__global__ __launch_bounds__(256,4) void k_conv1(const float* __restrict__ x,
    const float* __restrict__ w, const float* __restrict__ b,
    float* __restrict__ A, int n0){
  const int np = blockIdx.y, bx = blockIdx.x, t = threadIdx.x;
  const int och = bx&1, colh = (bx>>1)&1, rowt = bx>>2;   // rowt in [0,6)
  __shared__ float s_in[3][22][59];                       // odd stride: bank-spread
  const float* xb = x + (size_t)(n0+np)*3*112*112;
  const int g0 = rowt*18, c0 = colh*54;
  for(int idx=t; idx<3*22*58; idx+=256){
    int c=idx/(22*58), rem=idx%(22*58), rr=rem/58, cc=rem%58;
    s_in[c][rr][cc]=xb[(size_t)c*12544 + (g0+rr)*112 + c0+cc];
  }
  __syncthreads();
  const int item = t<243 ? t : 242;                       // 9 rows x 27 cols
  const int ly=item/27, ox=item%27;
  float acc[10][4];
  #pragma unroll
  for(int oo=0;oo<10;++oo){acc[oo][0]=0.f;acc[oo][1]=0.f;acc[oo][2]=0.f;acc[oo][3]=0.f;}
  #pragma unroll
  for(int c=0;c<3;++c){
    float win[6][6];
    #pragma unroll
    for(int r=0;r<6;++r)
      #pragma unroll
      for(int q=0;q<6;++q) win[r][q]=s_in[c][2*ly+r][2*ox+q];
    #pragma unroll
    for(int oo=0;oo<10;++oo){
      const float* wp = w + ((och*10+oo)*3+c)*25;         // uniform -> s_load
      #pragma unroll
      for(int ky=0;ky<5;++ky)
        #pragma unroll
        for(int kx=0;kx<5;++kx){
          float wv=wp[ky*5+kx];
          acc[oo][0]=fmaf(wv,win[ky][kx],acc[oo][0]);
          acc[oo][1]=fmaf(wv,win[ky][kx+1],acc[oo][1]);
          acc[oo][2]=fmaf(wv,win[ky+1][kx],acc[oo][2]);
          acc[oo][3]=fmaf(wv,win[ky+1][kx+1],acc[oo][3]);
        }
    }
  }
  if(t<243){
    const int oy=rowt*9+ly, gx=colh*27+ox;
    #pragma unroll
    for(int oo=0;oo<10;++oo){
      const int oc=och*10+oo;
      float m=fmaxf(fmaxf(acc[oo][0],acc[oo][1]),fmaxf(acc[oo][2],acc[oo][3]));
      A[(((size_t)np*20+oc)*54+oy)*54+gx]=fmaxf(m+b[oc],0.f);
    }
  }
}

// ------------------------------------------------------------------
// conv2 (20->50, 5x5) + bias + relu + 2x2 maxpool -> Bc[np][50][25][25]
// grid (25 = rt*5 + ocg, chunk). 128 thr = 2 waves. Each block: one
// ocg (10 output channels) x 5x25 output tile; input channel-chunked by 4.
// ------------------------------------------------------------------
__global__ __launch_bounds__(128,4) void k_conv2(const float* __restrict__ A,
    const float* __restrict__ w, const float* __restrict__ b,
    float* __restrict__ Bc){
  const int np = blockIdx.y, bx = blockIdx.x, t = threadIdx.x;
  const int ocg = bx%5, rt = bx/5;
  __shared__ float s_in[4][14][55];                       // odd stride
  const int item = t<125 ? t : 124;
  const int ly=item/25, ox=item%25;
  const int r0 = rt*10;
  float acc[10][4];
  #pragma unroll
  for(int oo=0;oo<10;++oo){acc[oo][0]=0.f;acc[oo][1]=0.f;acc[oo][2]=0.f;acc[oo][3]=0.f;}
  for(int ch=0; ch<20; ch+=4){
    __syncthreads();
    for(int idx=t; idx<3024; idx+=128){
      int c=idx/756, rem=idx%756, r=rem/54, cc=rem%54;
      s_in[c][r][cc]=A[(((size_t)np*20+ch+c)*54+r0+r)*54+cc];
    }
    __syncthreads();
    #pragma unroll
    for(int c=0;c<4;++c){
      float win[6][6];
      #pragma unroll
      for(int r=0;r<6;++r)
        #pragma unroll
        for(int q=0;q<6;++q) win[r][q]=s_in[c][2*ly+r][2*ox+q];
      #pragma unroll
      for(int oo=0;oo<10;++oo){
        const float* wp = w + ((ocg*10+oo)*20 + ch+c)*25;  // uniform -> s_load
        #pragma unroll
        for(int ky=0;ky<5;++ky)
          #pragma unroll
          for(int kx=0;kx<5;++kx){
            float wv=wp[ky*5+kx];
            acc[oo][0]=fmaf(wv,win[ky][kx],acc[oo][0]);
            acc[oo][1]=fmaf(wv,win[ky][kx+1],acc[oo][1]);
            acc[oo][2]=fmaf(wv,win[ky+1][kx],acc[oo][2]);
            acc[oo][3]=fmaf(wv,win[ky+1][kx+1],acc[oo][3]);
          }
      }
    }
  }
  if(t<125){
    const int oy=rt*5+ly;
    #pragma unroll
    for(int oo=0;oo<10;++oo){
      const int oc=ocg*10+oo;
      float m=fmaxf(fmaxf(acc[oo][0],acc[oo][1]),fmaxf(acc[oo][2],acc[oo][3]));
      Bc[(((size_t)np*50+oc)*25+oy)*25+ox]=fmaxf(m+b[oc],0.f);
    }
  }
}

// ------------------------------------------------------------------
// fc partials: Hp[ks][m_base+m0+r][n] = X_chunk[m0+r][:] . W[n][:]  (K split 32)
// grid 32*mtn*8 blocks; 256 thr = 4 waves. lane = m-row, wave*16+j = n
// (uniform -> scalar W loads). mrows guards short chunks.
// ------------------------------------------------------------------
__global__ __launch_bounds__(256,2) void k_fc(const float* __restrict__ X,
    const float* __restrict__ Wt, float* __restrict__ Hp, int m_base,
    int mtshift, int mrows){
  const int bid=blockIdx.x, t=threadIdx.x;
  const int ks=bid&31, rem=bid>>5;
  const int mt=rem&((1<<mtshift)-1), nt=rem>>mtshift;
  const int kbase=ks*1024;
  const int kend=(31250 < kbase+1024) ? 31250 : (kbase+1024);
  const int m0=mt*64, n0=nt*64;
  const int wave=__builtin_amdgcn_readfirstlane(t>>6);
  const int lane=t&63;
  __shared__ float s_X[64][65];
  float acc[16];
  #pragma unroll
  for(int j=0;j<16;++j) acc[j]=0.f;
  const float* wp[16];
  #pragma unroll
  for(int j=0;j<16;++j){
    int n=n0+wave*16+j;
    int nc = n<500 ? n : 499;           // clamp (guarded at store)
    wp[j]=Wt+(size_t)nc*31250;
  }
  for(int kb=kbase; kb<kend; kb+=64){
    __syncthreads();
    const bool full=(kb+64)<=kend;
    #pragma unroll
    for(int s2=0;s2<4;++s2){
      int q=t+256*s2;
      int r=q>>4, kk4=(q&15)*4;
      int rc = r<mrows ? r : mrows-1;   // clamp short chunks
      const float* src=X+(size_t)(m0+rc)*31250+kb+kk4;
      float v0,v1,v2,v3;
      if(full){ v0=src[0]; v1=src[1]; v2=src[2]; v3=src[3]; }
      else{
        v0=(kb+kk4+0<kend)?src[0]:0.f; v1=(kb+kk4+1<kend)?src[1]:0.f;
        v2=(kb+kk4+2<kend)?src[2]:0.f; v3=(kb+kk4+3<kend)?src[3]:0.f;
      }
      s_X[r][kk4]=v0; s_X[r][kk4+1]=v1; s_X[r][kk4+2]=v2; s_X[r][kk4+3]=v3;
    }
    __syncthreads();
    if(full){
      #pragma unroll 8
      for(int kk=0;kk<64;++kk){
        float xv=s_X[lane][kk];
        #pragma unroll
        for(int j=0;j<16;++j) acc[j]=fmaf(xv,wp[j][kb+kk],acc[j]);
      }
    } else {
      const int klim=kend-kb;
      for(int kk=0;kk<klim;++kk){
        float xv=s_X[lane][kk];
        #pragma unroll
        for(int j=0;j<16;++j) acc[j]=fmaf(xv,wp[j][kb+kk],acc[j]);
      }
    }
  }
  // coalesced store via LDS transpose
  __syncthreads();
  #pragma unroll
  for(int j=0;j<16;++j) s_X[lane][wave*16+j]=acc[j];
  __syncthreads();
  for(int idx=t; idx<4096; idx+=256){
    int r=idx>>6, c=idx&63, n=n0+c;
    if(r<mrows && n<500) Hp[((size_t)ks*512 + m_base+m0+r)*500+n]=s_X[r][c];
  }
}

// ------------------------------------------------------------------
// feat: relu(sum_ks Hp + fc_b) -> LN(500) | pos: LN(info@posw^T+posb, 12)
// feat[r][0..499]=f, [500..511]=p.  grid 128 x 256 (wave per row)
// ------------------------------------------------------------------
__global__ __launch_bounds__(256) void k_feat(const float* __restrict__ Hp,
    const float* __restrict__ fcb, const float* __restrict__ lnfg, const float* __restrict__ lnfb,
    const float* __restrict__ info, const float* __restrict__ posw, const float* __restrict__ posb,
    const float* __restrict__ lnpg, const float* __restrict__ lnpb, float* __restrict__ feat){
  const int t=threadIdx.x, wave=t>>6, lane=t&63;
  const int r=blockIdx.x*4+wave;
  float v[8];
  #pragma unroll
  for(int q=0;q<8;++q){
    int j=lane+64*q;
    if(j<500){
      float a=fcb[j];
      #pragma unroll
      for(int ks=0;ks<32;++ks) a+=Hp[((size_t)ks*512+r)*500+j];
      v[q]=fmaxf(a,0.f);
    } else v[q]=0.f;
  }
  float s=0.f;
  #pragma unroll
  for(int q=0;q<8;++q) s+=v[q];
  s=wsum(s);
  float mu=s/500.f;
  float ss=0.f;
  #pragma unroll
  for(int q=0;q<8;++q){ int j=lane+64*q; if(j<500){ float d=v[q]-mu; ss+=d*d; } }
  ss=wsum(ss);
  float inv=1.f/sqrtf(ss/500.f+EPSV);
  #pragma unroll
  for(int q=0;q<8;++q){
    int j=lane+64*q;
    if(j<500) feat[(size_t)r*512+j]=(v[q]-mu)*inv*lnfg[j]+lnfb[j];
  }
  if(lane==0){
    float ip[6];
    #pragma unroll
    for(int j=0;j<6;++j) ip[j]=info[r*6+j];
    float qv[12]; float mu2=0.f;
    #pragma unroll
    for(int k=0;k<12;++k){
      float a=posb[k];
      #pragma unroll
      for(int j=0;j<6;++j) a=fmaf(ip[j],posw[k*6+j],a);
      qv[k]=a; mu2+=a;
    }
    mu2*=(1.f/12.f);
    float ss2=0.f;
    #pragma unroll
    for(int k=0;k<12;++k){ float d=qv[k]-mu2; ss2+=d*d; }
    float inv2=1.f/sqrtf(ss2/12.f+EPSV);
    #pragma unroll
    for(int k=0;k<12;++k)
      feat[(size_t)r*512+500+k]=(qv[k]-mu2)*inv2*lnpg[k]+lnpb[k];
  }
}

// ------------------------------------------------------------------
// xw1[i][o] = feat[i,:512] . g1w[o,:512]   (per patch). grid (16 igroups, 8 p)
// ------------------------------------------------------------------
__global__ __launch_bounds__(256) void k_xw1(const float* __restrict__ feat,
    const float* __restrict__ w1, float* __restrict__ xw){
  const int p=blockIdx.y, ig=blockIdx.x, t=threadIdx.x;
  const int o=t;
  __shared__ float s_f[4][512];
  __shared__ float s_w[16][260];
  #pragma unroll
  for(int s2=0;s2<2;++s2){
    int q=t+256*s2; int node=q>>7, c4=(q&127)*4;
    float4 vv=*reinterpret_cast<const float4*>(&feat[((size_t)p*64+ig*4+node)*512+c4]);
    s_f[node][c4]=vv.x; s_f[node][c4+1]=vv.y; s_f[node][c4+2]=vv.z; s_f[node][c4+3]=vv.w;
  }
  float acc[4]={0.f,0.f,0.f,0.f};
  for(int k0=0;k0<512;k0+=16){
    __syncthreads();
    #pragma unroll
    for(int s2=0;s2<4;++s2){
      int qq=t+256*s2; int o2=qq>>2, kk4=(qq&3)*4;
      float4 vv=*reinterpret_cast<const float4*>(&w1[(size_t)o2*512+k0+kk4]);
      s_w[kk4][o2]=vv.x; s_w[kk4+1][o2]=vv.y; s_w[kk4+2][o2]=vv.z; s_w[kk4+3][o2]=vv.w;
    }
    __syncthreads();
    #pragma unroll
    for(int kk=0;kk<16;++kk){
      float wv=s_w[kk][o];
      #pragma unroll
      for(int m=0;m<4;++m) acc[m]=fmaf(s_f[m][k0+kk],wv,acc[m]);
    }
  }
  #pragma unroll
  for(int m=0;m<4;++m) xw[((size_t)p*64+ig*4+m)*256+o]=acc[m];
}

// ------------------------------------------------------------------
// per-patch GCN pipeline (one 1024-thr block per patch)
// ------------------------------------------------------------------
template<int NIN>
__device__ __forceinline__ void gemm_xw(int t, const float* __restrict__ xnp,
    const float* __restrict__ gw, float* __restrict__ xwp, float (*s_chunk)[65]){
  const int o=t&255, ig=t>>8;
  constexpr int IP=NIN/4;
  float acc[IP];
  #pragma unroll
  for(int m=0;m<IP;++m) acc[m]=0.f;
  for(int kc=0;kc<4;++kc){
    __syncthreads();
    if(t<NIN*16){
      int node=t>>4, c4=(t&15)*4;
      float4 vv=*reinterpret_cast<const float4*>(&xnp[(size_t)node*256+kc*64+c4]);
      s_chunk[node][c4]=vv.x; s_chunk[node][c4+1]=vv.y; s_chunk[node][c4+2]=vv.z; s_chunk[node][c4+3]=vv.w;
    }
    __syncthreads();
    const float* gwo = gw + (size_t)o*256 + kc*64;
    #pragma unroll 16
    for(int k=0;k<64;++k){
      float wv=gwo[k];
      #pragma unroll
      for(int m=0;m<IP;++m) acc[m]=fmaf(s_chunk[ig*IP+m][k],wv,acc[m]);
    }
  }
  #pragma unroll
  for(int m=0;m<IP;++m) xwp[(size_t)(ig*IP+m)*256+o]=acc[m];
  __syncthreads();
}

template<int NIN, int NOUT, bool BUILD_NEXT>
__device__ __forceinline__ void stage_body(int t,
    const float* __restrict__ xwp, float* __restrict__ zp, float* __restrict__ xnp,
    const float* __restrict__ gb, const float* __restrict__ pw, const float* __restrict__ pb,
    float (*s_na)[65], float* s_sin, float* s_score, float* s_vals, float* s_gate,
    float* s_dinv, int* s_perm, unsigned long long* s_adj, unsigned long long* s_adjN,
    float* s_res){
  const int lane=t&63, wave=t>>6;
  // combine: z[j][o] = relu(gb[o] + sum_i na[j][i]*xw[i][o])
  {
    const int o=t&255, jg=t>>8;
    constexpr int JP=NIN/4;
    float acc[JP];
    #pragma unroll
    for(int m=0;m<JP;++m) acc[m]=0.f;
    #pragma unroll 4
    for(int i=0;i<NIN;++i){
      float v=xwp[(size_t)i*256+o];
      #pragma unroll
      for(int m=0;m<JP;++m) acc[m]=fmaf(s_na[jg*JP+m][i],v,acc[m]);
    }
    float bo=gb[o];
    #pragma unroll
    for(int m=0;m<JP;++m) zp[(size_t)(jg*JP+m)*256+o]=fmaxf(acc[m]+bo,0.f);
  }
  __syncthreads();
  // scorer input: s_sin[i] = z[i,:] . pw
  for(int i=wave;i<NIN;i+=16){
    float a=0.f;
    #pragma unroll
    for(int q=0;q<4;++q){ int o=lane+64*q; a=fmaf(zp[(size_t)i*256+o],pw[o],a); }
    a=wsum(a);
    if(lane==0) s_sin[i]=a;
  }
  __syncthreads();
  if(t<NIN){
    float a=pb[0];
    for(int i=0;i<NIN;++i) a=fmaf(s_na[t][i],s_sin[i],a);
    s_score[t]=a;
  }
  __syncthreads();
  // top-k (stable descending, tie -> lower index; matches lax.top_k)
  if(t<NIN){
    float my=s_score[t]; int r=0;
    for(int k=0;k<NIN;++k){ float sk=s_score[k]; r += (int)((sk>my)||(sk==my && k<t)); }
    if(r<NOUT){ s_perm[r]=t; s_vals[r]=my; }
  }
  __syncthreads();
  if(t<NOUT) s_gate[t]=tanhf(s_vals[t]);
  __syncthreads();
  // xn[r][o] = z[perm[r]][o] * gate[r]
  {
    const int o=t&255, rg=t>>8;
    constexpr int RP=(NOUT+3)/4;
    #pragma unroll
    for(int m=0;m<RP;++m){
      int r=rg*RP+m;
      if(r<NOUT) xnp[(size_t)r*256+o]=zp[(size_t)s_perm[r]*256+o]*s_gate[r];
    }
  }
  __syncthreads();
  // res += concat(max, mean)
  if(t<256){
    float mx=-1e30f, sm=0.f;
    #pragma unroll 4
    for(int r=0;r<NOUT;++r){ float v=xnp[(size_t)r*256+t]; mx=fmaxf(mx,v); sm+=v; }
    s_res[t]+=mx; s_res[256+t]+=sm/(float)NOUT;
  }
  __syncthreads();
  if constexpr(BUILD_NEXT){
    if(t<NOUT){
      int pr=s_perm[t];
      unsigned long long bits=0ULL;
      unsigned long long rowa=s_adj[pr];
      for(int c=0;c<NOUT;++c)
        bits |= ((rowa>>s_perm[c])&1ULL)<<c;
      s_adjN[t]=bits;
    }
    __syncthreads();
    if(t<NOUT) s_adj[t]=s_adjN[t];
    __syncthreads();
    if(t<NOUT){
      int c=1;
      for(int i=0;i<NOUT;++i) c+=(int)((s_adj[i]>>t)&1ULL);
      s_dinv[t]=1.f/sqrtf((float)c);
    }
    __syncthreads();
    for(int q=t;q<NOUT*NOUT;q+=1024){
      int i=q/NOUT, j=q%NOUT;
      float cv=0.f;
      if(i==j || ((s_adj[i]>>j)&1ULL)) cv=s_dinv[i]*s_dinv[j];
      s_na[j][i]=cv;
    }
    __syncthreads();
  }
}

__global__ __launch_bounds__(1024) void k_patch(
    const float* __restrict__ feat, float* __restrict__ xwb,
    float* __restrict__ zb, float* __restrict__ xnb,
    const float* __restrict__ g1b,
    const float* __restrict__ g2w, const float* __restrict__ g2b,
    const float* __restrict__ g3w, const float* __restrict__ g3b,
    const float* __restrict__ p1w, const float* __restrict__ p1b,
    const float* __restrict__ p2w, const float* __restrict__ p2b,
    const float* __restrict__ p3w, const float* __restrict__ p3b,
    float* __restrict__ inst){
  const int p=blockIdx.x, t=threadIdx.x, lane=t&63, wave=t>>6;
  __shared__ float s_G[64][65];
  __shared__ float s_na[64][65];
  __shared__ float s_chunk[64][65];
  __shared__ float s_sin[64], s_score[64], s_vals[64], s_gate[64], s_dinv[64];
  __shared__ int s_perm[64];
  __shared__ unsigned long long s_adj[64], s_adjN[64];
  __shared__ float s_res[512];
  __shared__ float s_red[16];
  __shared__ float s_thr;

  const float* featp = feat + (size_t)p*64*512;
  float* xwp = xwb + (size_t)p*64*256;
  float* zp  = zb  + (size_t)p*64*256;
  float* xnp = xnb + (size_t)p*64*256;

  if(t<512) s_res[t]=0.f;

  // Gram matrix (64x64, K=512) via LDS chunks
  float gacc[4]={0.f,0.f,0.f,0.f};
  for(int kc=0;kc<8;++kc){
    __syncthreads();
    {
      int node=t>>4, c4=(t&15)*4;
      float4 vv=*reinterpret_cast<const float4*>(&featp[(size_t)node*512+kc*64+c4]);
      s_chunk[node][c4]=vv.x; s_chunk[node][c4+1]=vv.y; s_chunk[node][c4+2]=vv.z; s_chunk[node][c4+3]=vv.w;
    }
    __syncthreads();
    #pragma unroll
    for(int m=0;m<4;++m){
      int i=wave+16*m;
      float a=0.f;
      #pragma unroll 8
      for(int k=0;k<64;++k) a=fmaf(s_chunk[i][k],s_chunk[lane][k],a);
      gacc[m]+=a;
    }
  }
  __syncthreads();
  #pragma unroll
  for(int m=0;m<4;++m) s_G[wave+16*m][lane]=gacc[m];
  __syncthreads();
  // max pairwise sq-distance
  {
    float mx=-1e30f;
    #pragma unroll
    for(int m=0;m<4;++m){
      int i=wave+16*m;
      float d=s_G[i][i]+s_G[lane][lane]-2.f*s_G[i][lane];
      mx=fmaxf(mx,d);
    }
    mx=wmax_(mx);
    if(lane==0) s_red[wave]=mx;
  }
  __syncthreads();
  if(t==0){
    float mx=s_red[0];
    for(int i=1;i<16;++i) mx=fmaxf(mx,s_red[i]);
    s_thr=0.5f*mx;          // T = 0.5
  }
  __syncthreads();
  // adjacency bits (strict upper triangle, dist < thr strict)
  if(t<64){
    unsigned long long bits=0ULL;
    float thr=s_thr, gii=s_G[t][t];
    for(int j=t+1;j<64;++j){
      float d=gii+s_G[j][j]-2.f*s_G[t][j];
      if(d<thr) bits|=(1ULL<<j);
    }
    s_adj[t]=bits;
  }
  __syncthreads();
  if(t<64){
    int c=1;
    for(int i=0;i<64;++i) c+=(int)((s_adj[i]>>t)&1ULL);
    s_dinv[t]=1.f/sqrtf((float)c);
  }
  __syncthreads();
  for(int q=t;q<64*64;q+=1024){
    int i=q>>6, j=q&63;
    float cv=0.f;
    if(i==j || ((s_adj[i]>>j)&1ULL)) cv=s_dinv[i]*s_dinv[j];
    s_na[j][i]=cv;
  }
  __syncthreads();

  stage_body<64,48,true >(t,xwp,zp,xnp,g1b,p1w,p1b,s_na,s_sin,s_score,s_vals,s_gate,s_dinv,s_perm,s_adj,s_adjN,s_res);
  gemm_xw<48>(t,xnp,g2w,xwp,s_chunk);
  stage_body<48,36,true >(t,xwp,zp,xnp,g2b,p2w,p2b,s_na,s_sin,s_score,s_vals,s_gate,s_dinv,s_perm,s_adj,s_adjN,s_res);
  gemm_xw<36>(t,xnp,g3w,xwp,s_chunk);
  stage_body<36,27,false>(t,xwp,zp,xnp,g3b,p3w,p3b,s_na,s_sin,s_score,s_vals,s_gate,s_dinv,s_perm,s_adj,s_adjN,s_res);

  if(t<512) inst[(size_t)p*512+t]=s_res[t];
}

// ------------------------------------------------------------------
// attention MIL head + classifier + outputs (1 block)
// ------------------------------------------------------------------
__global__ __launch_bounds__(256) void k_final(
    const float* __restrict__ inst, const float* __restrict__ aw1, const float* __restrict__ ab1,
    const float* __restrict__ aw2, const float* __restrict__ ab2,
    const float* __restrict__ cw, const float* __restrict__ cb,
    const float* __restrict__ y, float* __restrict__ out){
  const int t=threadIdx.x;
  __shared__ float s_inst[8][512];
  __shared__ float s_t1[8][128];
  __shared__ float s_a[8];
  __shared__ float s_aw[8];
  __shared__ float s_bag[512];
  for(int q=t;q<4096;q+=256) s_inst[q>>9][q&511]=inst[q];
  __syncthreads();
  for(int q=t;q<1024;q+=256){
    int pp=q>>7, k=q&127;
    float a=ab1[k];
    for(int o=0;o<512;++o) a=fmaf(s_inst[pp][o],aw1[(size_t)k*512+o],a);
    s_t1[pp][k]=tanhf(a);
  }
  __syncthreads();
  if(t<8){
    float a=ab2[0];
    for(int k=0;k<128;++k) a=fmaf(s_t1[t][k],aw2[k],a);
    s_a[t]=a;
  }
  __syncthreads();
  if(t==0){
    float m=s_a[0];
    for(int i=1;i<8;++i) m=fmaxf(m,s_a[i]);
    float e[8]; float sm=0.f;
    for(int i=0;i<8;++i){ e[i]=expf(s_a[i]-m); sm+=e[i]; }
    for(int i=0;i<8;++i){ s_aw[i]=e[i]/sm; out[3+i]=s_aw[i]; }
  }
  __syncthreads();
  for(int o=t;o<512;o+=256){
    float a=0.f;
    #pragma unroll
    for(int pp=0;pp<8;++pp) a=fmaf(s_aw[pp],s_inst[pp][o],a);
    s_bag[o]=a;
  }
  __syncthreads();
  if(t<64){
    float a=0.f;
    #pragma unroll
    for(int q=0;q<8;++q){ int o=t+64*q; a=fmaf(s_bag[o],cw[o],a); }
    a=wsum(a);
    if(t==0){
      float logit=a+cb[0];
      float prob=1.f/(1.f+expf(-logit));
      float pc=fminf(fmaxf(prob,1e-5f),1.f-1e-5f);
      float pred=(prob>=0.5f)?1.f:0.f;
      float yy=y[0];
      float loss=-(yy*logf(pc)+(1.f-yy)*logf(1.f-pc));
      out[0]=pc; out[1]=pred; out[2]=loss;
    }
  }
}

// ------------------------------------------------------------------
extern "C" void kernel_launch(void* const* d_in, const int* in_sizes, int n_in,
                              void* d_out, int out_size, void* d_ws, size_t ws_size,
                              hipStream_t stream){
  (void)in_sizes; (void)n_in; (void)out_size;
  const float* x   =(const float*)d_in[0];
  const float* info=(const float*)d_in[1];
  const float* y   =(const float*)d_in[2];
  const float* c1w=(const float*)d_in[4];  const float* c1b=(const float*)d_in[5];
  const float* c2w=(const float*)d_in[6];  const float* c2b=(const float*)d_in[7];
  const float* fcw=(const float*)d_in[8];  const float* fcb=(const float*)d_in[9];
  const float* lnfg=(const float*)d_in[10];const float* lnfb=(const float*)d_in[11];
  const float* posw=(const float*)d_in[12];const float* posb=(const float*)d_in[13];
  const float* lnpg=(const float*)d_in[14];const float* lnpb=(const float*)d_in[15];
  const float* g1w=(const float*)d_in[16]; const float* g1b=(const float*)d_in[17];
  const float* g2w=(const float*)d_in[18]; const float* g2b=(const float*)d_in[19];
  const float* g3w=(const float*)d_in[20]; const float* g3b=(const float*)d_in[21];
  const float* p1w=(const float*)d_in[22]; const float* p1b=(const float*)d_in[23];
  const float* p2w=(const float*)d_in[24]; const float* p2b=(const float*)d_in[25];
  const float* p3w=(const float*)d_in[26]; const float* p3b=(const float*)d_in[27];
  const float* aw1=(const float*)d_in[28]; const float* ab1=(const float*)d_in[29];
  const float* aw2=(const float*)d_in[30]; const float* ab2=(const float*)d_in[31];
  const float* cw =(const float*)d_in[32]; const float* cb =(const float*)d_in[33];
  float* out=(float*)d_out;
  float* W=(float*)d_ws;

  // tiered chunking to fit ws_size (constant across calls -> graph-safe)
  int chunk;
  if      (ws_size >= (size_t)20316416*4) chunk=128;   // 81.3 MB
  else if (ws_size >= (size_t)14583936*4) chunk=64;    // 58.3 MB
  else                                    chunk=32;    // 46.9 MB (best effort)
  const int nch = 512/chunk;
  const int mtn = chunk>=128 ? 2 : 1;
  const int mtshift = chunk>=128 ? 1 : 0;
  const int mrows = chunk<64 ? chunk : 64;

  const size_t A_OFF  = 0;
  const size_t BC_OFF = (size_t)chunk*58320;           // A elems
  const size_t HP_OFF = BC_OFF + (size_t)chunk*31250;  // Bc elems
  const size_t FEAT_OFF = HP_OFF + (size_t)32*512*500;
  const size_t XW_OFF  = FEAT_OFF+262144;
  const size_t Z_OFF   = XW_OFF+131072;
  const size_t XN_OFF  = Z_OFF+131072;
  const size_t INST_OFF= XN_OFF+131072;

  for(int ch=0;ch<nch;++ch){
    k_conv1<<<dim3(24,chunk),256,0,stream>>>(x,c1w,c1b,W+A_OFF,ch*chunk);
    k_conv2<<<dim3(25,chunk),128,0,stream>>>(W+A_OFF,c2w,c2b,W+BC_OFF);
    k_fc<<<dim3(32*mtn*8),256,0,stream>>>(W+BC_OFF,fcw,W+HP_OFF,ch*chunk,mtshift,mrows);
  }
  k_feat<<<dim3(128),256,0,stream>>>(W+HP_OFF,fcb,lnfg,lnfb,info,posw,posb,lnpg,lnpb,W+FEAT_OFF);
  k_xw1<<<dim3(16,8),256,0,stream>>>(W+FEAT_OFF,g1w,W+XW_OFF);
  k_patch<<<dim3(8),1024,0,stream>>>(W+FEAT_OFF,W+XW_OFF,W+Z_OFF,W+XN_OFF,
      g1b,g2w,g2b,g3w,g3b,p1w,p1b,p2w,p2b,p3w,p3b,W+INST_OFF);
  k_final<<<1,256,0,stream>>>(W+INST_OFF,aw1,ab1,aw2,ab2,cw,cb,y,out);
}

// Round 6
// 3155.195 us; speedup vs baseline: 1.0125x; 1.0125x over previous
//
#include <hip/hip_runtime.h>
#include <math.h>

#define EPSV 1e-5f

__device__ __forceinline__ float wsum(float v){
  #pragma unroll
  for(int m=32;m;m>>=1) v += __shfl_xor(v,m);
  return v;
}
__device__ __forceinline__ float wmax_(float v){
  #pragma unroll
  for(int m=32;m;m>>=1) v = fmaxf(v,__shfl_xor(v,m));
  return v;
}

// ------------------------------------------------------------------
// conv1 (3->20, 5x5, VALID) + bias + relu + 2x2 maxpool -> A[np][20][54][54]
// grid (24 = rowt*4 + colh*2 + och, chunk). 256 thr = 4 waves.
// ky-outer rolling 2-row scheme: live set = acc[10][4] + 12 row regs, all
// statically indexed -> no LDS rematerialization (R5 lesson: VGPR=64 remat).
// ------------------------------------------------------------------
__global__ __launch_bounds__(256,4) void k_conv1(const float* __restrict__ x,
    const float* __restrict__ w, const float* __restrict__ b,
    float* __restrict__ A, int n0){
  const int np = blockIdx.y, bx = blockIdx.x, t = threadIdx.x;
  const int och = bx&1, colh = (bx>>1)&1, rowt = bx>>2;   // rowt in [0,6)
  __shared__ float s_in[3][22][59];
  const float* xb = x + (size_t)(n0+np)*3*112*112;
  const int g0 = rowt*18, c0 = colh*54;
  for(int idx=t; idx<3*22*58; idx+=256){
    int c=idx/(22*58), rem=idx%(22*58), rr=rem/58, cc=rem%58;
    s_in[c][rr][cc]=xb[(size_t)c*12544 + (g0+rr)*112 + c0+cc];
  }
  __syncthreads();
  const int item = t<243 ? t : 242;                       // 9 rows x 27 cols
  const int ly=item/27, ox=item%27;
  float acc[10][4];
  #pragma unroll
  for(int oo=0;oo<10;++oo){acc[oo][0]=0.f;acc[oo][1]=0.f;acc[oo][2]=0.f;acc[oo][3]=0.f;}

  auto LOADR=[&](float (&R)[6], int c, int rr){
    #pragma unroll
    for(int q=0;q<6;++q) R[q]=s_in[c][2*ly+rr][2*ox+q];
  };
  auto PROC=[&](int ky, const float (&RA)[6], const float (&RB)[6], const float* wc){
    #pragma unroll
    for(int oo=0;oo<10;++oo){
      const float* wp = wc + oo*75;                       // uniform -> s_load
      #pragma unroll
      for(int kx=0;kx<5;++kx){
        float wv=wp[ky*5+kx];
        acc[oo][0]=fmaf(wv,RA[kx],acc[oo][0]);
        acc[oo][1]=fmaf(wv,RA[kx+1],acc[oo][1]);
        acc[oo][2]=fmaf(wv,RB[kx],acc[oo][2]);
        acc[oo][3]=fmaf(wv,RB[kx+1],acc[oo][3]);
      }
    }
  };
  #pragma unroll
  for(int c=0;c<3;++c){
    const float* wc = w + (och*10)*75 + c*25;
    float rA[6], rB[6];
    LOADR(rA,c,0); LOADR(rB,c,1);
    PROC(0,rA,rB,wc);
    LOADR(rA,c,2); PROC(1,rB,rA,wc);
    LOADR(rB,c,3); PROC(2,rA,rB,wc);
    LOADR(rA,c,4); PROC(3,rB,rA,wc);
    LOADR(rB,c,5); PROC(4,rA,rB,wc);
  }
  if(t<243){
    const int oy=rowt*9+ly, gx=colh*27+ox;
    #pragma unroll
    for(int oo=0;oo<10;++oo){
      const int oc=och*10+oo;
      float m=fmaxf(fmaxf(acc[oo][0],acc[oo][1]),fmaxf(acc[oo][2],acc[oo][3]));
      A[(((size_t)np*20+oc)*54+oy)*54+gx]=fmaxf(m+b[oc],0.f);
    }
  }
}

// ------------------------------------------------------------------
// conv2 (20->50, 5x5) + bias + relu + 2x2 maxpool -> Bc[np][50][25][25]
// grid (25 = rt*5 + ocg, chunk). 128 thr = 2 waves. Same rolling scheme.
// ------------------------------------------------------------------
__global__ __launch_bounds__(128,4) void k_conv2(const float* __restrict__ A,
    const float* __restrict__ w, const float* __restrict__ b,
    float* __restrict__ Bc){
  const int np = blockIdx.y, bx = blockIdx.x, t = threadIdx.x;
  const int ocg = bx%5, rt = bx/5;
  __shared__ float s_in[4][14][55];
  const int item = t<125 ? t : 124;
  const int ly=item/25, ox=item%25;
  const int r0 = rt*10;
  float acc[10][4];
  #pragma unroll
  for(int oo=0;oo<10;++oo){acc[oo][0]=0.f;acc[oo][1]=0.f;acc[oo][2]=0.f;acc[oo][3]=0.f;}

  auto LOADR=[&](float (&R)[6], int c, int rr){
    #pragma unroll
    for(int q=0;q<6;++q) R[q]=s_in[c][2*ly+rr][2*ox+q];
  };
  auto PROC=[&](int ky, const float (&RA)[6], const float (&RB)[6], const float* wc){
    #pragma unroll
    for(int oo=0;oo<10;++oo){
      const float* wp = wc + oo*500;                      // uniform -> s_load
      #pragma unroll
      for(int kx=0;kx<5;++kx){
        float wv=wp[ky*5+kx];
        acc[oo][0]=fmaf(wv,RA[kx],acc[oo][0]);
        acc[oo][1]=fmaf(wv,RA[kx+1],acc[oo][1]);
        acc[oo][2]=fmaf(wv,RB[kx],acc[oo][2]);
        acc[oo][3]=fmaf(wv,RB[kx+1],acc[oo][3]);
      }
    }
  };
  for(int ch=0; ch<20; ch+=4){
    __syncthreads();
    for(int idx=t; idx<3024; idx+=128){
      int c=idx/756, rem=idx%756, r=rem/54, cc=rem%54;
      s_in[c][r][cc]=A[(((size_t)np*20+ch+c)*54+r0+r)*54+cc];
    }
    __syncthreads();
    #pragma unroll
    for(int c=0;c<4;++c){
      const float* wc = w + ((ocg*10)*20 + ch+c)*25;
      float rA[6], rB[6];
      LOADR(rA,c,0); LOADR(rB,c,1);
      PROC(0,rA,rB,wc);
      LOADR(rA,c,2); PROC(1,rB,rA,wc);
      LOADR(rB,c,3); PROC(2,rA,rB,wc);
      LOADR(rA,c,4); PROC(3,rB,rA,wc);
      LOADR(rB,c,5); PROC(4,rA,rB,wc);
    }
  }
  if(t<125){
    const int oy=rt*5+ly;
    #pragma unroll
    for(int oo=0;oo<10;++oo){
      const int oc=ocg*10+oo;
      float m=fmaxf(fmaxf(acc[oo][0],acc[oo][1]),fmaxf(acc[oo][2],acc[oo][3]));
      Bc[(((size_t)np*50+oc)*25+oy)*25+ox]=fmaxf(m+b[oc],0.f);
    }
  }
}

// ------------------------------------------------------------------
// fc partials: Hp[ks][m_base+m0+r][n] = X_chunk[m0+r][:] . W[n][:]  (K split 32)
// grid 32*mtn*8 blocks; 256 thr = 4 waves. lane = m-row, wave*16+j = n
// (uniform -> scalar W loads). mrows guards short chunks.
// ------------------------------------------------------------------
__global__ __launch_bounds__(256,2) void k_fc(const float* __restrict__ X,
    const float* __restrict__ Wt, float* __restrict__ Hp, int m_base,
    int mtshift, int mrows){
  const int bid=blockIdx.x, t=threadIdx.x;
  const int ks=bid&31, rem=bid>>5;
  const int mt=rem&((1<<mtshift)-1), nt=rem>>mtshift;
  const int kbase=ks*1024;
  const int kend=(31250 < kbase+1024) ? 31250 : (kbase+1024);
  const int m0=mt*64, n0=nt*64;
  const int wave=__builtin_amdgcn_readfirstlane(t>>6);
  const int lane=t&63;
  __shared__ float s_X[64][65];
  float acc[16];
  #pragma unroll
  for(int j=0;j<16;++j) acc[j]=0.f;
  const float* wp[16];
  #pragma unroll
  for(int j=0;j<16;++j){
    int n=n0+wave*16+j;
    int nc = n<500 ? n : 499;           // clamp (guarded at store)
    wp[j]=Wt+(size_t)nc*31250;
  }
  for(int kb=kbase; kb<kend; kb+=64){
    __syncthreads();
    const bool full=(kb+64)<=kend;
    #pragma unroll
    for(int s2=0;s2<4;++s2){
      int q=t+256*s2;
      int r=q>>4, kk4=(q&15)*4;
      int rc = r<mrows ? r : mrows-1;   // clamp short chunks
      const float* src=X+(size_t)(m0+rc)*31250+kb+kk4;
      float v0,v1,v2,v3;
      if(full){ v0=src[0]; v1=src[1]; v2=src[2]; v3=src[3]; }
      else{
        v0=(kb+kk4+0<kend)?src[0]:0.f; v1=(kb+kk4+1<kend)?src[1]:0.f;
        v2=(kb+kk4+2<kend)?src[2]:0.f; v3=(kb+kk4+3<kend)?src[3]:0.f;
      }
      s_X[r][kk4]=v0; s_X[r][kk4+1]=v1; s_X[r][kk4+2]=v2; s_X[r][kk4+3]=v3;
    }
    __syncthreads();
    if(full){
      #pragma unroll 8
      for(int kk=0;kk<64;++kk){
        float xv=s_X[lane][kk];
        #pragma unroll
        for(int j=0;j<16;++j) acc[j]=fmaf(xv,wp[j][kb+kk],acc[j]);
      }
    } else {
      const int klim=kend-kb;
      for(int kk=0;kk<klim;++kk){
        float xv=s_X[lane][kk];
        #pragma unroll
        for(int j=0;j<16;++j) acc[j]=fmaf(xv,wp[j][kb+kk],acc[j]);
      }
    }
  }
  // coalesced store via LDS transpose
  __syncthreads();
  #pragma unroll
  for(int j=0;j<16;++j) s_X[lane][wave*16+j]=acc[j];
  __syncthreads();
  for(int idx=t; idx<4096; idx+=256){
    int r=idx>>6, c=idx&63, n=n0+c;
    if(r<mrows && n<500) Hp[((size_t)ks*512 + m_base+m0+r)*500+n]=s_X[r][c];
  }
}

// ------------------------------------------------------------------
// feat: relu(sum_ks Hp + fc_b) -> LN(500) | pos: LN(info@posw^T+posb, 12)
// feat[r][0..499]=f, [500..511]=p.  grid 128 x 256 (wave per row)
// ------------------------------------------------------------------
__global__ __launch_bounds__(256) void k_feat(const float* __restrict__ Hp,
    const float* __restrict__ fcb, const float* __restrict__ lnfg, const float* __restrict__ lnfb,
    const float* __restrict__ info, const float* __restrict__ posw, const float* __restrict__ posb,
    const float* __restrict__ lnpg, const float* __restrict__ lnpb, float* __restrict__ feat){
  const int t=threadIdx.x, wave=t>>6, lane=t&63;
  const int r=blockIdx.x*4+wave;
  float v[8];
  #pragma unroll
  for(int q=0;q<8;++q){
    int j=lane+64*q;
    if(j<500){
      float a=fcb[j];
      #pragma unroll
      for(int ks=0;ks<32;++ks) a+=Hp[((size_t)ks*512+r)*500+j];
      v[q]=fmaxf(a,0.f);
    } else v[q]=0.f;
  }
  float s=0.f;
  #pragma unroll
  for(int q=0;q<8;++q) s+=v[q];
  s=wsum(s);
  float mu=s/500.f;
  float ss=0.f;
  #pragma unroll
  for(int q=0;q<8;++q){ int j=lane+64*q; if(j<500){ float d=v[q]-mu; ss+=d*d; } }
  ss=wsum(ss);
  float inv=1.f/sqrtf(ss/500.f+EPSV);
  #pragma unroll
  for(int q=0;q<8;++q){
    int j=lane+64*q;
    if(j<500) feat[(size_t)r*512+j]=(v[q]-mu)*inv*lnfg[j]+lnfb[j];
  }
  if(lane==0){
    float ip[6];
    #pragma unroll
    for(int j=0;j<6;++j) ip[j]=info[r*6+j];
    float qv[12]; float mu2=0.f;
    #pragma unroll
    for(int k=0;k<12;++k){
      float a=posb[k];
      #pragma unroll
      for(int j=0;j<6;++j) a=fmaf(ip[j],posw[k*6+j],a);
      qv[k]=a; mu2+=a;
    }
    mu2*=(1.f/12.f);
    float ss2=0.f;
    #pragma unroll
    for(int k=0;k<12;++k){ float d=qv[k]-mu2; ss2+=d*d; }
    float inv2=1.f/sqrtf(ss2/12.f+EPSV);
    #pragma unroll
    for(int k=0;k<12;++k)
      feat[(size_t)r*512+500+k]=(qv[k]-mu2)*inv2*lnpg[k]+lnpb[k];
  }
}

// ------------------------------------------------------------------
// xw1[i][o] = feat[i,:512] . g1w[o,:512]   (per patch). grid (16 igroups, 8 p)
// ------------------------------------------------------------------
__global__ __launch_bounds__(256) void k_xw1(const float* __restrict__ feat,
    const float* __restrict__ w1, float* __restrict__ xw){
  const int p=blockIdx.y, ig=blockIdx.x, t=threadIdx.x;
  const int o=t;
  __shared__ float s_f[4][512];
  __shared__ float s_w[16][260];
  #pragma unroll
  for(int s2=0;s2<2;++s2){
    int q=t+256*s2; int node=q>>7, c4=(q&127)*4;
    float4 vv=*reinterpret_cast<const float4*>(&feat[((size_t)p*64+ig*4+node)*512+c4]);
    s_f[node][c4]=vv.x; s_f[node][c4+1]=vv.y; s_f[node][c4+2]=vv.z; s_f[node][c4+3]=vv.w;
  }
  float acc[4]={0.f,0.f,0.f,0.f};
  for(int k0=0;k0<512;k0+=16){
    __syncthreads();
    #pragma unroll
    for(int s2=0;s2<4;++s2){
      int qq=t+256*s2; int o2=qq>>2, kk4=(qq&3)*4;
      float4 vv=*reinterpret_cast<const float4*>(&w1[(size_t)o2*512+k0+kk4]);
      s_w[kk4][o2]=vv.x; s_w[kk4+1][o2]=vv.y; s_w[kk4+2][o2]=vv.z; s_w[kk4+3][o2]=vv.w;
    }
    __syncthreads();
    #pragma unroll
    for(int kk=0;kk<16;++kk){
      float wv=s_w[kk][o];
      #pragma unroll
      for(int m=0;m<4;++m) acc[m]=fmaf(s_f[m][k0+kk],wv,acc[m]);
    }
  }
  #pragma unroll
  for(int m=0;m<4;++m) xw[((size_t)p*64+ig*4+m)*256+o]=acc[m];
}

// ------------------------------------------------------------------
// per-patch GCN pipeline (one 1024-thr block per patch)
// ------------------------------------------------------------------
template<int NIN>
__device__ __forceinline__ void gemm_xw(int t, const float* __restrict__ xnp,
    const float* __restrict__ gw, float* __restrict__ xwp, float (*s_chunk)[65]){
  const int o=t&255, ig=t>>8;
  constexpr int IP=NIN/4;
  float acc[IP];
  #pragma unroll
  for(int m=0;m<IP;++m) acc[m]=0.f;
  for(int kc=0;kc<4;++kc){
    __syncthreads();
    if(t<NIN*16){
      int node=t>>4, c4=(t&15)*4;
      float4 vv=*reinterpret_cast<const float4*>(&xnp[(size_t)node*256+kc*64+c4]);
      s_chunk[node][c4]=vv.x; s_chunk[node][c4+1]=vv.y; s_chunk[node][c4+2]=vv.z; s_chunk[node][c4+3]=vv.w;
    }
    __syncthreads();
    const float* gwo = gw + (size_t)o*256 + kc*64;
    #pragma unroll 16
    for(int k=0;k<64;++k){
      float wv=gwo[k];
      #pragma unroll
      for(int m=0;m<IP;++m) acc[m]=fmaf(s_chunk[ig*IP+m][k],wv,acc[m]);
    }
  }
  #pragma unroll
  for(int m=0;m<IP;++m) xwp[(size_t)(ig*IP+m)*256+o]=acc[m];
  __syncthreads();
}

template<int NIN, int NOUT, bool BUILD_NEXT>
__device__ __forceinline__ void stage_body(int t,
    const float* __restrict__ xwp, float* __restrict__ zp, float* __restrict__ xnp,
    const float* __restrict__ gb, const float* __restrict__ pw, const float* __restrict__ pb,
    float (*s_na)[65], float* s_sin, float* s_score, float* s_vals, float* s_gate,
    float* s_dinv, int* s_perm, unsigned long long* s_adj, unsigned long long* s_adjN,
    float* s_res){
  const int lane=t&63, wave=t>>6;
  // combine: z[j][o] = relu(gb[o] + sum_i na[j][i]*xw[i][o])
  {
    const int o=t&255, jg=t>>8;
    constexpr int JP=NIN/4;
    float acc[JP];
    #pragma unroll
    for(int m=0;m<JP;++m) acc[m]=0.f;
    #pragma unroll 4
    for(int i=0;i<NIN;++i){
      float v=xwp[(size_t)i*256+o];
      #pragma unroll
      for(int m=0;m<JP;++m) acc[m]=fmaf(s_na[jg*JP+m][i],v,acc[m]);
    }
    float bo=gb[o];
    #pragma unroll
    for(int m=0;m<JP;++m) zp[(size_t)(jg*JP+m)*256+o]=fmaxf(acc[m]+bo,0.f);
  }
  __syncthreads();
  // scorer input: s_sin[i] = z[i,:] . pw
  for(int i=wave;i<NIN;i+=16){
    float a=0.f;
    #pragma unroll
    for(int q=0;q<4;++q){ int o=lane+64*q; a=fmaf(zp[(size_t)i*256+o],pw[o],a); }
    a=wsum(a);
    if(lane==0) s_sin[i]=a;
  }
  __syncthreads();
  if(t<NIN){
    float a=pb[0];
    for(int i=0;i<NIN;++i) a=fmaf(s_na[t][i],s_sin[i],a);
    s_score[t]=a;
  }
  __syncthreads();
  // top-k (stable descending, tie -> lower index; matches lax.top_k)
  if(t<NIN){
    float my=s_score[t]; int r=0;
    for(int k=0;k<NIN;++k){ float sk=s_score[k]; r += (int)((sk>my)||(sk==my && k<t)); }
    if(r<NOUT){ s_perm[r]=t; s_vals[r]=my; }
  }
  __syncthreads();
  if(t<NOUT) s_gate[t]=tanhf(s_vals[t]);
  __syncthreads();
  // xn[r][o] = z[perm[r]][o] * gate[r]
  {
    const int o=t&255, rg=t>>8;
    constexpr int RP=(NOUT+3)/4;
    #pragma unroll
    for(int m=0;m<RP;++m){
      int r=rg*RP+m;
      if(r<NOUT) xnp[(size_t)r*256+o]=zp[(size_t)s_perm[r]*256+o]*s_gate[r];
    }
  }
  __syncthreads();
  // res += concat(max, mean)
  if(t<256){
    float mx=-1e30f, sm=0.f;
    #pragma unroll 4
    for(int r=0;r<NOUT;++r){ float v=xnp[(size_t)r*256+t]; mx=fmaxf(mx,v); sm+=v; }
    s_res[t]+=mx; s_res[256+t]+=sm/(float)NOUT;
  }
  __syncthreads();
  if constexpr(BUILD_NEXT){
    if(t<NOUT){
      int pr=s_perm[t];
      unsigned long long bits=0ULL;
      unsigned long long rowa=s_adj[pr];
      for(int c=0;c<NOUT;++c)
        bits |= ((rowa>>s_perm[c])&1ULL)<<c;
      s_adjN[t]=bits;
    }
    __syncthreads();
    if(t<NOUT) s_adj[t]=s_adjN[t];
    __syncthreads();
    if(t<NOUT){
      int c=1;
      for(int i=0;i<NOUT;++i) c+=(int)((s_adj[i]>>t)&1ULL);
      s_dinv[t]=1.f/sqrtf((float)c);
    }
    __syncthreads();
    for(int q=t;q<NOUT*NOUT;q+=1024){
      int i=q/NOUT, j=q%NOUT;
      float cv=0.f;
      if(i==j || ((s_adj[i]>>j)&1ULL)) cv=s_dinv[i]*s_dinv[j];
      s_na[j][i]=cv;
    }
    __syncthreads();
  }
}

__global__ __launch_bounds__(1024) void k_patch(
    const float* __restrict__ feat, float* __restrict__ xwb,
    float* __restrict__ zb, float* __restrict__ xnb,
    const float* __restrict__ g1b,
    const float* __restrict__ g2w, const float* __restrict__ g2b,
    const float* __restrict__ g3w, const float* __restrict__ g3b,
    const float* __restrict__ p1w, const float* __restrict__ p1b,
    const float* __restrict__ p2w, const float* __restrict__ p2b,
    const float* __restrict__ p3w, const float* __restrict__ p3b,
    float* __restrict__ inst){
  const int p=blockIdx.x, t=threadIdx.x, lane=t&63, wave=t>>6;
  __shared__ float s_G[64][65];
  __shared__ float s_na[64][65];
  __shared__ float s_chunk[64][65];
  __shared__ float s_sin[64], s_score[64], s_vals[64], s_gate[64], s_dinv[64];
  __shared__ int s_perm[64];
  __shared__ unsigned long long s_adj[64], s_adjN[64];
  __shared__ float s_res[512];
  __shared__ float s_red[16];
  __shared__ float s_thr;

  const float* featp = feat + (size_t)p*64*512;
  float* xwp = xwb + (size_t)p*64*256;
  float* zp  = zb  + (size_t)p*64*256;
  float* xnp = xnb + (size_t)p*64*256;

  if(t<512) s_res[t]=0.f;

  // Gram matrix (64x64, K=512) via LDS chunks
  float gacc[4]={0.f,0.f,0.f,0.f};
  for(int kc=0;kc<8;++kc){
    __syncthreads();
    {
      int node=t>>4, c4=(t&15)*4;
      float4 vv=*reinterpret_cast<const float4*>(&featp[(size_t)node*512+kc*64+c4]);
      s_chunk[node][c4]=vv.x; s_chunk[node][c4+1]=vv.y; s_chunk[node][c4+2]=vv.z; s_chunk[node][c4+3]=vv.w;
    }
    __syncthreads();
    #pragma unroll
    for(int m=0;m<4;++m){
      int i=wave+16*m;
      float a=0.f;
      #pragma unroll 8
      for(int k=0;k<64;++k) a=fmaf(s_chunk[i][k],s_chunk[lane][k],a);
      gacc[m]+=a;
    }
  }
  __syncthreads();
  #pragma unroll
  for(int m=0;m<4;++m) s_G[wave+16*m][lane]=gacc[m];
  __syncthreads();
  // max pairwise sq-distance
  {
    float mx=-1e30f;
    #pragma unroll
    for(int m=0;m<4;++m){
      int i=wave+16*m;
      float d=s_G[i][i]+s_G[lane][lane]-2.f*s_G[i][lane];
      mx=fmaxf(mx,d);
    }
    mx=wmax_(mx);
    if(lane==0) s_red[wave]=mx;
  }
  __syncthreads();
  if(t==0){
    float mx=s_red[0];
    for(int i=1;i<16;++i) mx=fmaxf(mx,s_red[i]);
    s_thr=0.5f*mx;          // T = 0.5
  }
  __syncthreads();
  // adjacency bits (strict upper triangle, dist < thr strict)
  if(t<64){
    unsigned long long bits=0ULL;
    float thr=s_thr, gii=s_G[t][t];
    for(int j=t+1;j<64;++j){
      float d=gii+s_G[j][j]-2.f*s_G[t][j];
      if(d<thr) bits|=(1ULL<<j);
    }
    s_adj[t]=bits;
  }
  __syncthreads();
  if(t<64){
    int c=1;
    for(int i=0;i<64;++i) c+=(int)((s_adj[i]>>t)&1ULL);
    s_dinv[t]=1.f/sqrtf((float)c);
  }
  __syncthreads();
  for(int q=t;q<64*64;q+=1024){
    int i=q>>6, j=q&63;
    float cv=0.f;
    if(i==j || ((s_adj[i]>>j)&1ULL)) cv=s_dinv[i]*s_dinv[j];
    s_na[j][i]=cv;
  }
  __syncthreads();

  stage_body<64,48,true >(t,xwp,zp,xnp,g1b,p1w,p1b,s_na,s_sin,s_score,s_vals,s_gate,s_dinv,s_perm,s_adj,s_adjN,s_res);
  gemm_xw<48>(t,xnp,g2w,xwp,s_chunk);
  stage_body<48,36,true >(t,xwp,zp,xnp,g2b,p2w,p2b,s_na,s_sin,s_score,s_vals,s_gate,s_dinv,s_perm,s_adj,s_adjN,s_res);
  gemm_xw<36>(t,xnp,g3w,xwp,s_chunk);
  stage_body<36,27,false>(t,xwp,zp,xnp,g3b,p3w,p3b,s_na,s_sin,s_score,s_vals,s_gate,s_dinv,s_perm,s_adj,s_adjN,s_res);

  if(t<512) inst[(size_t)p*512+t]=s_res[t];
}

// ------------------------------------------------------------------
// attention MIL head + classifier + outputs (1 block)
// ------------------------------------------------------------------
__global__ __launch_bounds__(256) void k_final(
    const float* __restrict__ inst, const float* __restrict__ aw1, const float* __restrict__ ab1,
    const float* __restrict__ aw2, const float* __restrict__ ab2,
    const float* __restrict__ cw, const float* __restrict__ cb,
    const float* __restrict__ y, float* __restrict__ out){
  const int t=threadIdx.x;
  __shared__ float s_inst[8][512];
  __shared__ float s_t1[8][128];
  __shared__ float s_a[8];
  __shared__ float s_aw[8];
  __shared__ float s_bag[512];
  for(int q=t;q<4096;q+=256) s_inst[q>>9][q&511]=inst[q];
  __syncthreads();
  for(int q=t;q<1024;q+=256){
    int pp=q>>7, k=q&127;
    float a=ab1[k];
    for(int o=0;o<512;++o) a=fmaf(s_inst[pp][o],aw1[(size_t)k*512+o],a);
    s_t1[pp][k]=tanhf(a);
  }
  __syncthreads();
  if(t<8){
    float a=ab2[0];
    for(int k=0;k<128;++k) a=fmaf(s_t1[t][k],aw2[k],a);
    s_a[t]=a;
  }
  __syncthreads();
  if(t==0){
    float m=s_a[0];
    for(int i=1;i<8;++i) m=fmaxf(m,s_a[i]);
    float e[8]; float sm=0.f;
    for(int i=0;i<8;++i){ e[i]=expf(s_a[i]-m); sm+=e[i]; }
    for(int i=0;i<8;++i){ s_aw[i]=e[i]/sm; out[3+i]=s_aw[i]; }
  }
  __syncthreads();
  for(int o=t;o<512;o+=256){
    float a=0.f;
    #pragma unroll
    for(int pp=0;pp<8;++pp) a=fmaf(s_aw[pp],s_inst[pp][o],a);
    s_bag[o]=a;
  }
  __syncthreads();
  if(t<64){
    float a=0.f;
    #pragma unroll
    for(int q=0;q<8;++q){ int o=t+64*q; a=fmaf(s_bag[o],cw[o],a); }
    a=wsum(a);
    if(t==0){
      float logit=a+cb[0];
      float prob=1.f/(1.f+expf(-logit));
      float pc=fminf(fmaxf(prob,1e-5f),1.f-1e-5f);
      float pred=(prob>=0.5f)?1.f:0.f;
      float yy=y[0];
      float loss=-(yy*logf(pc)+(1.f-yy)*logf(1.f-pc));
      out[0]=pc; out[1]=pred; out[2]=loss;
    }
  }
}

// ------------------------------------------------------------------
extern "C" void kernel_launch(void* const* d_in, const int* in_sizes, int n_in,
                              void* d_out, int out_size, void* d_ws, size_t ws_size,
                              hipStream_t stream){
  (void)in_sizes; (void)n_in; (void)out_size;
  const float* x   =(const float*)d_in[0];
  const float* info=(const float*)d_in[1];
  const float* y   =(const float*)d_in[2];
  const float* c1w=(const float*)d_in[4];  const float* c1b=(const float*)d_in[5];
  const float* c2w=(const float*)d_in[6];  const float* c2b=(const float*)d_in[7];
  const float* fcw=(const float*)d_in[8];  const float* fcb=(const float*)d_in[9];
  const float* lnfg=(const float*)d_in[10];const float* lnfb=(const float*)d_in[11];
  const float* posw=(const float*)d_in[12];const float* posb=(const float*)d_in[13];
  const float* lnpg=(const float*)d_in[14];const float* lnpb=(const float*)d_in[15];
  const float* g1w=(const float*)d_in[16]; const float* g1b=(const float*)d_in[17];
  const float* g2w=(const float*)d_in[18]; const float* g2b=(const float*)d_in[19];
  const float* g3w=(const float*)d_in[20]; const float* g3b=(const float*)d_in[21];
  const float* p1w=(const float*)d_in[22]; const float* p1b=(const float*)d_in[23];
  const float* p2w=(const float*)d_in[24]; const float* p2b=(const float*)d_in[25];
  const float* p3w=(const float*)d_in[26]; const float* p3b=(const float*)d_in[27];
  const float* aw1=(const float*)d_in[28]; const float* ab1=(const float*)d_in[29];
  const float* aw2=(const float*)d_in[30]; const float* ab2=(const float*)d_in[31];
  const float* cw =(const float*)d_in[32]; const float* cb =(const float*)d_in[33];
  float* out=(float*)d_out;
  float* W=(float*)d_ws;

  // tiered chunking to fit ws_size (constant across calls -> graph-safe)
  int chunk;
  if      (ws_size >= (size_t)20316416*4) chunk=128;   // 81.3 MB
  else if (ws_size >= (size_t)14583936*4) chunk=64;    // 58.3 MB
  else                                    chunk=32;    // 46.9 MB (best effort)
  const int nch = 512/chunk;
  const int mtn = chunk>=128 ? 2 : 1;
  const int mtshift = chunk>=128 ? 1 : 0;
  const int mrows = chunk<64 ? chunk : 64;

  const size_t A_OFF  = 0;
  const size_t BC_OFF = (size_t)chunk*58320;           // A elems
  const size_t HP_OFF = BC_OFF + (size_t)chunk*31250;  // Bc elems
  const size_t FEAT_OFF = HP_OFF + (size_t)32*512*500;
  const size_t XW_OFF  = FEAT_OFF+262144;
  const size_t Z_OFF   = XW_OFF+131072;
  const size_t XN_OFF  = Z_OFF+131072;
  const size_t INST_OFF= XN_OFF+131072;

  for(int ch=0;ch<nch;++ch){
    k_conv1<<<dim3(24,chunk),256,0,stream>>>(x,c1w,c1b,W+A_OFF,ch*chunk);
    k_conv2<<<dim3(25,chunk),128,0,stream>>>(W+A_OFF,c2w,c2b,W+BC_OFF);
    k_fc<<<dim3(32*mtn*8),256,0,stream>>>(W+BC_OFF,fcw,W+HP_OFF,ch*chunk,mtshift,mrows);
  }
  k_feat<<<dim3(128),256,0,stream>>>(W+HP_OFF,fcb,lnfg,lnfb,info,posw,posb,lnpg,lnpb,W+FEAT_OFF);
  k_xw1<<<dim3(16,8),256,0,stream>>>(W+FEAT_OFF,g1w,W+XW_OFF);
  k_patch<<<dim3(8),1024,0,stream>>>(W+FEAT_OFF,W+XW_OFF,W+Z_OFF,W+XN_OFF,
      g1b,g2w,g2b,g3w,g3b,p1w,p1b,p2w,p2b,p3w,p3b,W+INST_OFF);
  k_final<<<1,256,0,stream>>>(W+INST_OFF,aw1,ab1,aw2,ab2,cw,cb,y,out);
}

// Round 7
// 2580.658 us; speedup vs baseline: 1.2380x; 1.2226x over previous
//
#include <hip/hip_runtime.h>
#include <math.h>

#define EPSV 1e-5f

__device__ __forceinline__ float wsum(float v){
  #pragma unroll
  for(int m=32;m;m>>=1) v += __shfl_xor(v,m);
  return v;
}
__device__ __forceinline__ float wmax_(float v){
  #pragma unroll
  for(int m=32;m;m>>=1) v = fmaxf(v,__shfl_xor(v,m));
  return v;
}

// ------------------------------------------------------------------
// conv1 (3->20, 5x5, VALID) + bias + relu + 2x2 maxpool -> A[np][20][54][54]
// grid (24 = rowt*4 + colh*2 + och, chunk). 256 thr.
// COMPACT runtime (c,ky) loops (R6 lesson: full unroll = 42KB body > 32KB
// I-cache, and interleaved s_loads stall FMA stream). Body: batch-load 50
// weights -> regs, 12 row floats -> regs, then pure 200-FMA burst. ~2KB code.
// ------------------------------------------------------------------
__global__ __launch_bounds__(256,2) void k_conv1(const float* __restrict__ x,
    const float* __restrict__ w, const float* __restrict__ b,
    float* __restrict__ A, int n0){
  const int np = blockIdx.y, bx = blockIdx.x, t = threadIdx.x;
  const int och = bx&1, colh = (bx>>1)&1, rowt = bx>>2;   // rowt in [0,6)
  __shared__ float s_in[3][22][59];
  const float* xb = x + (size_t)(n0+np)*3*112*112;
  const int g0 = rowt*18, c0 = colh*54;
  for(int idx=t; idx<3*22*58; idx+=256){
    int c=idx/(22*58), rem=idx%(22*58), rr=rem/58, cc=rem%58;
    s_in[c][rr][cc]=xb[(size_t)c*12544 + (g0+rr)*112 + c0+cc];
  }
  __syncthreads();
  const int item = t<243 ? t : 242;                       // 9 rows x 27 cols
  const int ly=item/27, ox=item%27;
  float acc[10][4];
  #pragma unroll
  for(int oo=0;oo<10;++oo){acc[oo][0]=0.f;acc[oo][1]=0.f;acc[oo][2]=0.f;acc[oo][3]=0.f;}
  const float* wb_ = w + (och*10)*75;                     // uniform
  #pragma unroll 1
  for(int c=0;c<3;++c){
    const float* sb = &s_in[c][2*ly][2*ox];
    const float* wc = wb_ + c*25;
    #pragma unroll 1
    for(int ky=0;ky<5;++ky){
      float wv[10][5];                                    // uniform vals
      #pragma unroll
      for(int oo=0;oo<10;++oo)
        #pragma unroll
        for(int kx=0;kx<5;++kx) wv[oo][kx]=wc[oo*75+ky*5+kx];
      float ra[6], rb2[6];
      #pragma unroll
      for(int q=0;q<6;++q) ra[q]=sb[ky*59+q];
      #pragma unroll
      for(int q=0;q<6;++q) rb2[q]=sb[(ky+1)*59+q];
      #pragma unroll
      for(int oo=0;oo<10;++oo)
        #pragma unroll
        for(int kx=0;kx<5;++kx){
          float wvv=wv[oo][kx];
          acc[oo][0]=fmaf(wvv,ra[kx],acc[oo][0]);
          acc[oo][1]=fmaf(wvv,ra[kx+1],acc[oo][1]);
          acc[oo][2]=fmaf(wvv,rb2[kx],acc[oo][2]);
          acc[oo][3]=fmaf(wvv,rb2[kx+1],acc[oo][3]);
        }
    }
  }
  if(t<243){
    const int oy=rowt*9+ly, gx=colh*27+ox;
    #pragma unroll
    for(int oo=0;oo<10;++oo){
      const int oc=och*10+oo;
      float m=fmaxf(fmaxf(acc[oo][0],acc[oo][1]),fmaxf(acc[oo][2],acc[oo][3]));
      A[(((size_t)np*20+oc)*54+oy)*54+gx]=fmaxf(m+b[oc],0.f);
    }
  }
}

// ------------------------------------------------------------------
// conv2 (20->50, 5x5) + bias + relu + 2x2 maxpool -> Bc[np][50][25][25]
// grid (25 = rt*5 + ocg, chunk). 128 thr. Same compact-body scheme.
// ------------------------------------------------------------------
__global__ __launch_bounds__(128,2) void k_conv2(const float* __restrict__ A,
    const float* __restrict__ w, const float* __restrict__ b,
    float* __restrict__ Bc){
  const int np = blockIdx.y, bx = blockIdx.x, t = threadIdx.x;
  const int ocg = bx%5, rt = bx/5;
  __shared__ float s_in[4][14][55];
  const int item = t<125 ? t : 124;
  const int ly=item/25, ox=item%25;
  const int r0 = rt*10;
  float acc[10][4];
  #pragma unroll
  for(int oo=0;oo<10;++oo){acc[oo][0]=0.f;acc[oo][1]=0.f;acc[oo][2]=0.f;acc[oo][3]=0.f;}
  #pragma unroll 1
  for(int ch=0; ch<20; ch+=4){
    __syncthreads();
    for(int idx=t; idx<3024; idx+=128){
      int c=idx/756, rem=idx%756, r=rem/54, cc=rem%54;
      s_in[c][r][cc]=A[(((size_t)np*20+ch+c)*54+r0+r)*54+cc];
    }
    __syncthreads();
    #pragma unroll 1
    for(int c=0;c<4;++c){
      const float* sb = &s_in[c][2*ly][2*ox];
      const float* wc = w + ((ocg*10)*20 + ch+c)*25;      // uniform
      #pragma unroll 1
      for(int ky=0;ky<5;++ky){
        float wv[10][5];                                  // uniform vals
        #pragma unroll
        for(int oo=0;oo<10;++oo)
          #pragma unroll
          for(int kx=0;kx<5;++kx) wv[oo][kx]=wc[oo*500+ky*5+kx];
        float ra[6], rb2[6];
        #pragma unroll
        for(int q=0;q<6;++q) ra[q]=sb[ky*55+q];
        #pragma unroll
        for(int q=0;q<6;++q) rb2[q]=sb[(ky+1)*55+q];
        #pragma unroll
        for(int oo=0;oo<10;++oo)
          #pragma unroll
          for(int kx=0;kx<5;++kx){
            float wvv=wv[oo][kx];
            acc[oo][0]=fmaf(wvv,ra[kx],acc[oo][0]);
            acc[oo][1]=fmaf(wvv,ra[kx+1],acc[oo][1]);
            acc[oo][2]=fmaf(wvv,rb2[kx],acc[oo][2]);
            acc[oo][3]=fmaf(wvv,rb2[kx+1],acc[oo][3]);
          }
      }
    }
  }
  if(t<125){
    const int oy=rt*5+ly;
    #pragma unroll
    for(int oo=0;oo<10;++oo){
      const int oc=ocg*10+oo;
      float m=fmaxf(fmaxf(acc[oo][0],acc[oo][1]),fmaxf(acc[oo][2],acc[oo][3]));
      Bc[(((size_t)np*50+oc)*25+oy)*25+ox]=fmaxf(m+b[oc],0.f);
    }
  }
}

// ------------------------------------------------------------------
// fc partials: Hp[ks][m_base+m0+r][n] = X_chunk[m0+r][:] . W[n][:]  (K split 32)
// grid 32*mtn*8 blocks; 256 thr = 4 waves. lane = m-row, wave*16+j = n
// (uniform -> scalar W loads). mrows guards short chunks.
// ------------------------------------------------------------------
__global__ __launch_bounds__(256,2) void k_fc(const float* __restrict__ X,
    const float* __restrict__ Wt, float* __restrict__ Hp, int m_base,
    int mtshift, int mrows){
  const int bid=blockIdx.x, t=threadIdx.x;
  const int ks=bid&31, rem=bid>>5;
  const int mt=rem&((1<<mtshift)-1), nt=rem>>mtshift;
  const int kbase=ks*1024;
  const int kend=(31250 < kbase+1024) ? 31250 : (kbase+1024);
  const int m0=mt*64, n0=nt*64;
  const int wave=__builtin_amdgcn_readfirstlane(t>>6);
  const int lane=t&63;
  __shared__ float s_X[64][65];
  float acc[16];
  #pragma unroll
  for(int j=0;j<16;++j) acc[j]=0.f;
  const float* wp[16];
  #pragma unroll
  for(int j=0;j<16;++j){
    int n=n0+wave*16+j;
    int nc = n<500 ? n : 499;           // clamp (guarded at store)
    wp[j]=Wt+(size_t)nc*31250;
  }
  for(int kb=kbase; kb<kend; kb+=64){
    __syncthreads();
    const bool full=(kb+64)<=kend;
    #pragma unroll
    for(int s2=0;s2<4;++s2){
      int q=t+256*s2;
      int r=q>>4, kk4=(q&15)*4;
      int rc = r<mrows ? r : mrows-1;   // clamp short chunks
      const float* src=X+(size_t)(m0+rc)*31250+kb+kk4;
      float v0,v1,v2,v3;
      if(full){ v0=src[0]; v1=src[1]; v2=src[2]; v3=src[3]; }
      else{
        v0=(kb+kk4+0<kend)?src[0]:0.f; v1=(kb+kk4+1<kend)?src[1]:0.f;
        v2=(kb+kk4+2<kend)?src[2]:0.f; v3=(kb+kk4+3<kend)?src[3]:0.f;
      }
      s_X[r][kk4]=v0; s_X[r][kk4+1]=v1; s_X[r][kk4+2]=v2; s_X[r][kk4+3]=v3;
    }
    __syncthreads();
    if(full){
      #pragma unroll 8
      for(int kk=0;kk<64;++kk){
        float xv=s_X[lane][kk];
        #pragma unroll
        for(int j=0;j<16;++j) acc[j]=fmaf(xv,wp[j][kb+kk],acc[j]);
      }
    } else {
      const int klim=kend-kb;
      for(int kk=0;kk<klim;++kk){
        float xv=s_X[lane][kk];
        #pragma unroll
        for(int j=0;j<16;++j) acc[j]=fmaf(xv,wp[j][kb+kk],acc[j]);
      }
    }
  }
  // coalesced store via LDS transpose
  __syncthreads();
  #pragma unroll
  for(int j=0;j<16;++j) s_X[lane][wave*16+j]=acc[j];
  __syncthreads();
  for(int idx=t; idx<4096; idx+=256){
    int r=idx>>6, c=idx&63, n=n0+c;
    if(r<mrows && n<500) Hp[((size_t)ks*512 + m_base+m0+r)*500+n]=s_X[r][c];
  }
}

// ------------------------------------------------------------------
// feat: relu(sum_ks Hp + fc_b) -> LN(500) | pos: LN(info@posw^T+posb, 12)
// feat[r][0..499]=f, [500..511]=p.  grid 128 x 256 (wave per row)
// ------------------------------------------------------------------
__global__ __launch_bounds__(256) void k_feat(const float* __restrict__ Hp,
    const float* __restrict__ fcb, const float* __restrict__ lnfg, const float* __restrict__ lnfb,
    const float* __restrict__ info, const float* __restrict__ posw, const float* __restrict__ posb,
    const float* __restrict__ lnpg, const float* __restrict__ lnpb, float* __restrict__ feat){
  const int t=threadIdx.x, wave=t>>6, lane=t&63;
  const int r=blockIdx.x*4+wave;
  float v[8];
  #pragma unroll
  for(int q=0;q<8;++q){
    int j=lane+64*q;
    if(j<500){
      float a=fcb[j];
      #pragma unroll
      for(int ks=0;ks<32;++ks) a+=Hp[((size_t)ks*512+r)*500+j];
      v[q]=fmaxf(a,0.f);
    } else v[q]=0.f;
  }
  float s=0.f;
  #pragma unroll
  for(int q=0;q<8;++q) s+=v[q];
  s=wsum(s);
  float mu=s/500.f;
  float ss=0.f;
  #pragma unroll
  for(int q=0;q<8;++q){ int j=lane+64*q; if(j<500){ float d=v[q]-mu; ss+=d*d; } }
  ss=wsum(ss);
  float inv=1.f/sqrtf(ss/500.f+EPSV);
  #pragma unroll
  for(int q=0;q<8;++q){
    int j=lane+64*q;
    if(j<500) feat[(size_t)r*512+j]=(v[q]-mu)*inv*lnfg[j]+lnfb[j];
  }
  if(lane==0){
    float ip[6];
    #pragma unroll
    for(int j=0;j<6;++j) ip[j]=info[r*6+j];
    float qv[12]; float mu2=0.f;
    #pragma unroll
    for(int k=0;k<12;++k){
      float a=posb[k];
      #pragma unroll
      for(int j=0;j<6;++j) a=fmaf(ip[j],posw[k*6+j],a);
      qv[k]=a; mu2+=a;
    }
    mu2*=(1.f/12.f);
    float ss2=0.f;
    #pragma unroll
    for(int k=0;k<12;++k){ float d=qv[k]-mu2; ss2+=d*d; }
    float inv2=1.f/sqrtf(ss2/12.f+EPSV);
    #pragma unroll
    for(int k=0;k<12;++k)
      feat[(size_t)r*512+500+k]=(qv[k]-mu2)*inv2*lnpg[k]+lnpb[k];
  }
}

// ------------------------------------------------------------------
// xw1[i][o] = feat[i,:512] . g1w[o,:512]   (per patch). grid (16 igroups, 8 p)
// ------------------------------------------------------------------
__global__ __launch_bounds__(256) void k_xw1(const float* __restrict__ feat,
    const float* __restrict__ w1, float* __restrict__ xw){
  const int p=blockIdx.y, ig=blockIdx.x, t=threadIdx.x;
  const int o=t;
  __shared__ float s_f[4][512];
  __shared__ float s_w[16][260];
  #pragma unroll
  for(int s2=0;s2<2;++s2){
    int q=t+256*s2; int node=q>>7, c4=(q&127)*4;
    float4 vv=*reinterpret_cast<const float4*>(&feat[((size_t)p*64+ig*4+node)*512+c4]);
    s_f[node][c4]=vv.x; s_f[node][c4+1]=vv.y; s_f[node][c4+2]=vv.z; s_f[node][c4+3]=vv.w;
  }
  float acc[4]={0.f,0.f,0.f,0.f};
  for(int k0=0;k0<512;k0+=16){
    __syncthreads();
    #pragma unroll
    for(int s2=0;s2<4;++s2){
      int qq=t+256*s2; int o2=qq>>2, kk4=(qq&3)*4;
      float4 vv=*reinterpret_cast<const float4*>(&w1[(size_t)o2*512+k0+kk4]);
      s_w[kk4][o2]=vv.x; s_w[kk4+1][o2]=vv.y; s_w[kk4+2][o2]=vv.z; s_w[kk4+3][o2]=vv.w;
    }
    __syncthreads();
    #pragma unroll
    for(int kk=0;kk<16;++kk){
      float wv=s_w[kk][o];
      #pragma unroll
      for(int m=0;m<4;++m) acc[m]=fmaf(s_f[m][k0+kk],wv,acc[m]);
    }
  }
  #pragma unroll
  for(int m=0;m<4;++m) xw[((size_t)p*64+ig*4+m)*256+o]=acc[m];
}

// ------------------------------------------------------------------
// per-patch GCN pipeline (one 1024-thr block per patch)
// ------------------------------------------------------------------
template<int NIN>
__device__ __forceinline__ void gemm_xw(int t, const float* __restrict__ xnp,
    const float* __restrict__ gw, float* __restrict__ xwp, float (*s_chunk)[65]){
  const int o=t&255, ig=t>>8;
  constexpr int IP=NIN/4;
  float acc[IP];
  #pragma unroll
  for(int m=0;m<IP;++m) acc[m]=0.f;
  for(int kc=0;kc<4;++kc){
    __syncthreads();
    if(t<NIN*16){
      int node=t>>4, c4=(t&15)*4;
      float4 vv=*reinterpret_cast<const float4*>(&xnp[(size_t)node*256+kc*64+c4]);
      s_chunk[node][c4]=vv.x; s_chunk[node][c4+1]=vv.y; s_chunk[node][c4+2]=vv.z; s_chunk[node][c4+3]=vv.w;
    }
    __syncthreads();
    const float* gwo = gw + (size_t)o*256 + kc*64;
    #pragma unroll 16
    for(int k=0;k<64;++k){
      float wv=gwo[k];
      #pragma unroll
      for(int m=0;m<IP;++m) acc[m]=fmaf(s_chunk[ig*IP+m][k],wv,acc[m]);
    }
  }
  #pragma unroll
  for(int m=0;m<IP;++m) xwp[(size_t)(ig*IP+m)*256+o]=acc[m];
  __syncthreads();
}

template<int NIN, int NOUT, bool BUILD_NEXT>
__device__ __forceinline__ void stage_body(int t,
    const float* __restrict__ xwp, float* __restrict__ zp, float* __restrict__ xnp,
    const float* __restrict__ gb, const float* __restrict__ pw, const float* __restrict__ pb,
    float (*s_na)[65], float* s_sin, float* s_score, float* s_vals, float* s_gate,
    float* s_dinv, int* s_perm, unsigned long long* s_adj, unsigned long long* s_adjN,
    float* s_res){
  const int lane=t&63, wave=t>>6;
  // combine: z[j][o] = relu(gb[o] + sum_i na[j][i]*xw[i][o])
  {
    const int o=t&255, jg=t>>8;
    constexpr int JP=NIN/4;
    float acc[JP];
    #pragma unroll
    for(int m=0;m<JP;++m) acc[m]=0.f;
    #pragma unroll 4
    for(int i=0;i<NIN;++i){
      float v=xwp[(size_t)i*256+o];
      #pragma unroll
      for(int m=0;m<JP;++m) acc[m]=fmaf(s_na[jg*JP+m][i],v,acc[m]);
    }
    float bo=gb[o];
    #pragma unroll
    for(int m=0;m<JP;++m) zp[(size_t)(jg*JP+m)*256+o]=fmaxf(acc[m]+bo,0.f);
  }
  __syncthreads();
  // scorer input: s_sin[i] = z[i,:] . pw
  for(int i=wave;i<NIN;i+=16){
    float a=0.f;
    #pragma unroll
    for(int q=0;q<4;++q){ int o=lane+64*q; a=fmaf(zp[(size_t)i*256+o],pw[o],a); }
    a=wsum(a);
    if(lane==0) s_sin[i]=a;
  }
  __syncthreads();
  if(t<NIN){
    float a=pb[0];
    for(int i=0;i<NIN;++i) a=fmaf(s_na[t][i],s_sin[i],a);
    s_score[t]=a;
  }
  __syncthreads();
  // top-k (stable descending, tie -> lower index; matches lax.top_k)
  if(t<NIN){
    float my=s_score[t]; int r=0;
    for(int k=0;k<NIN;++k){ float sk=s_score[k]; r += (int)((sk>my)||(sk==my && k<t)); }
    if(r<NOUT){ s_perm[r]=t; s_vals[r]=my; }
  }
  __syncthreads();
  if(t<NOUT) s_gate[t]=tanhf(s_vals[t]);
  __syncthreads();
  // xn[r][o] = z[perm[r]][o] * gate[r]
  {
    const int o=t&255, rg=t>>8;
    constexpr int RP=(NOUT+3)/4;
    #pragma unroll
    for(int m=0;m<RP;++m){
      int r=rg*RP+m;
      if(r<NOUT) xnp[(size_t)r*256+o]=zp[(size_t)s_perm[r]*256+o]*s_gate[r];
    }
  }
  __syncthreads();
  // res += concat(max, mean)
  if(t<256){
    float mx=-1e30f, sm=0.f;
    #pragma unroll 4
    for(int r=0;r<NOUT;++r){ float v=xnp[(size_t)r*256+t]; mx=fmaxf(mx,v); sm+=v; }
    s_res[t]+=mx; s_res[256+t]+=sm/(float)NOUT;
  }
  __syncthreads();
  if constexpr(BUILD_NEXT){
    if(t<NOUT){
      int pr=s_perm[t];
      unsigned long long bits=0ULL;
      unsigned long long rowa=s_adj[pr];
      for(int c=0;c<NOUT;++c)
        bits |= ((rowa>>s_perm[c])&1ULL)<<c;
      s_adjN[t]=bits;
    }
    __syncthreads();
    if(t<NOUT) s_adj[t]=s_adjN[t];
    __syncthreads();
    if(t<NOUT){
      int c=1;
      for(int i=0;i<NOUT;++i) c+=(int)((s_adj[i]>>t)&1ULL);
      s_dinv[t]=1.f/sqrtf((float)c);
    }
    __syncthreads();
    for(int q=t;q<NOUT*NOUT;q+=1024){
      int i=q/NOUT, j=q%NOUT;
      float cv=0.f;
      if(i==j || ((s_adj[i]>>j)&1ULL)) cv=s_dinv[i]*s_dinv[j];
      s_na[j][i]=cv;
    }
    __syncthreads();
  }
}

__global__ __launch_bounds__(1024) void k_patch(
    const float* __restrict__ feat, float* __restrict__ xwb,
    float* __restrict__ zb, float* __restrict__ xnb,
    const float* __restrict__ g1b,
    const float* __restrict__ g2w, const float* __restrict__ g2b,
    const float* __restrict__ g3w, const float* __restrict__ g3b,
    const float* __restrict__ p1w, const float* __restrict__ p1b,
    const float* __restrict__ p2w, const float* __restrict__ p2b,
    const float* __restrict__ p3w, const float* __restrict__ p3b,
    float* __restrict__ inst){
  const int p=blockIdx.x, t=threadIdx.x, lane=t&63, wave=t>>6;
  __shared__ float s_G[64][65];
  __shared__ float s_na[64][65];
  __shared__ float s_chunk[64][65];
  __shared__ float s_sin[64], s_score[64], s_vals[64], s_gate[64], s_dinv[64];
  __shared__ int s_perm[64];
  __shared__ unsigned long long s_adj[64], s_adjN[64];
  __shared__ float s_res[512];
  __shared__ float s_red[16];
  __shared__ float s_thr;

  const float* featp = feat + (size_t)p*64*512;
  float* xwp = xwb + (size_t)p*64*256;
  float* zp  = zb  + (size_t)p*64*256;
  float* xnp = xnb + (size_t)p*64*256;

  if(t<512) s_res[t]=0.f;

  // Gram matrix (64x64, K=512) via LDS chunks
  float gacc[4]={0.f,0.f,0.f,0.f};
  for(int kc=0;kc<8;++kc){
    __syncthreads();
    {
      int node=t>>4, c4=(t&15)*4;
      float4 vv=*reinterpret_cast<const float4*>(&featp[(size_t)node*512+kc*64+c4]);
      s_chunk[node][c4]=vv.x; s_chunk[node][c4+1]=vv.y; s_chunk[node][c4+2]=vv.z; s_chunk[node][c4+3]=vv.w;
    }
    __syncthreads();
    #pragma unroll
    for(int m=0;m<4;++m){
      int i=wave+16*m;
      float a=0.f;
      #pragma unroll 8
      for(int k=0;k<64;++k) a=fmaf(s_chunk[i][k],s_chunk[lane][k],a);
      gacc[m]+=a;
    }
  }
  __syncthreads();
  #pragma unroll
  for(int m=0;m<4;++m) s_G[wave+16*m][lane]=gacc[m];
  __syncthreads();
  // max pairwise sq-distance
  {
    float mx=-1e30f;
    #pragma unroll
    for(int m=0;m<4;++m){
      int i=wave+16*m;
      float d=s_G[i][i]+s_G[lane][lane]-2.f*s_G[i][lane];
      mx=fmaxf(mx,d);
    }
    mx=wmax_(mx);
    if(lane==0) s_red[wave]=mx;
  }
  __syncthreads();
  if(t==0){
    float mx=s_red[0];
    for(int i=1;i<16;++i) mx=fmaxf(mx,s_red[i]);
    s_thr=0.5f*mx;          // T = 0.5
  }
  __syncthreads();
  // adjacency bits (strict upper triangle, dist < thr strict)
  if(t<64){
    unsigned long long bits=0ULL;
    float thr=s_thr, gii=s_G[t][t];
    for(int j=t+1;j<64;++j){
      float d=gii+s_G[j][j]-2.f*s_G[t][j];
      if(d<thr) bits|=(1ULL<<j);
    }
    s_adj[t]=bits;
  }
  __syncthreads();
  if(t<64){
    int c=1;
    for(int i=0;i<64;++i) c+=(int)((s_adj[i]>>t)&1ULL);
    s_dinv[t]=1.f/sqrtf((float)c);
  }
  __syncthreads();
  for(int q=t;q<64*64;q+=1024){
    int i=q>>6, j=q&63;
    float cv=0.f;
    if(i==j || ((s_adj[i]>>j)&1ULL)) cv=s_dinv[i]*s_dinv[j];
    s_na[j][i]=cv;
  }
  __syncthreads();

  stage_body<64,48,true >(t,xwp,zp,xnp,g1b,p1w,p1b,s_na,s_sin,s_score,s_vals,s_gate,s_dinv,s_perm,s_adj,s_adjN,s_res);
  gemm_xw<48>(t,xnp,g2w,xwp,s_chunk);
  stage_body<48,36,true >(t,xwp,zp,xnp,g2b,p2w,p2b,s_na,s_sin,s_score,s_vals,s_gate,s_dinv,s_perm,s_adj,s_adjN,s_res);
  gemm_xw<36>(t,xnp,g3w,xwp,s_chunk);
  stage_body<36,27,false>(t,xwp,zp,xnp,g3b,p3w,p3b,s_na,s_sin,s_score,s_vals,s_gate,s_dinv,s_perm,s_adj,s_adjN,s_res);

  if(t<512) inst[(size_t)p*512+t]=s_res[t];
}

// ------------------------------------------------------------------
// attention MIL head + classifier + outputs (1 block)
// ------------------------------------------------------------------
__global__ __launch_bounds__(256) void k_final(
    const float* __restrict__ inst, const float* __restrict__ aw1, const float* __restrict__ ab1,
    const float* __restrict__ aw2, const float* __restrict__ ab2,
    const float* __restrict__ cw, const float* __restrict__ cb,
    const float* __restrict__ y, float* __restrict__ out){
  const int t=threadIdx.x;
  __shared__ float s_inst[8][512];
  __shared__ float s_t1[8][128];
  __shared__ float s_a[8];
  __shared__ float s_aw[8];
  __shared__ float s_bag[512];
  for(int q=t;q<4096;q+=256) s_inst[q>>9][q&511]=inst[q];
  __syncthreads();
  for(int q=t;q<1024;q+=256){
    int pp=q>>7, k=q&127;
    float a=ab1[k];
    for(int o=0;o<512;++o) a=fmaf(s_inst[pp][o],aw1[(size_t)k*512+o],a);
    s_t1[pp][k]=tanhf(a);
  }
  __syncthreads();
  if(t<8){
    float a=ab2[0];
    for(int k=0;k<128;++k) a=fmaf(s_t1[t][k],aw2[k],a);
    s_a[t]=a;
  }
  __syncthreads();
  if(t==0){
    float m=s_a[0];
    for(int i=1;i<8;++i) m=fmaxf(m,s_a[i]);
    float e[8]; float sm=0.f;
    for(int i=0;i<8;++i){ e[i]=expf(s_a[i]-m); sm+=e[i]; }
    for(int i=0;i<8;++i){ s_aw[i]=e[i]/sm; out[3+i]=s_aw[i]; }
  }
  __syncthreads();
  for(int o=t;o<512;o+=256){
    float a=0.f;
    #pragma unroll
    for(int pp=0;pp<8;++pp) a=fmaf(s_aw[pp],s_inst[pp][o],a);
    s_bag[o]=a;
  }
  __syncthreads();
  if(t<64){
    float a=0.f;
    #pragma unroll
    for(int q=0;q<8;++q){ int o=t+64*q; a=fmaf(s_bag[o],cw[o],a); }
    a=wsum(a);
    if(t==0){
      float logit=a+cb[0];
      float prob=1.f/(1.f+expf(-logit));
      float pc=fminf(fmaxf(prob,1e-5f),1.f-1e-5f);
      float pred=(prob>=0.5f)?1.f:0.f;
      float yy=y[0];
      float loss=-(yy*logf(pc)+(1.f-yy)*logf(1.f-pc));
      out[0]=pc; out[1]=pred; out[2]=loss;
    }
  }
}

// ------------------------------------------------------------------
extern "C" void kernel_launch(void* const* d_in, const int* in_sizes, int n_in,
                              void* d_out, int out_size, void* d_ws, size_t ws_size,
                              hipStream_t stream){
  (void)in_sizes; (void)n_in; (void)out_size;
  const float* x   =(const float*)d_in[0];
  const float* info=(const float*)d_in[1];
  const float* y   =(const float*)d_in[2];
  const float* c1w=(const float*)d_in[4];  const float* c1b=(const float*)d_in[5];
  const float* c2w=(const float*)d_in[6];  const float* c2b=(const float*)d_in[7];
  const float* fcw=(const float*)d_in[8];  const float* fcb=(const float*)d_in[9];
  const float* lnfg=(const float*)d_in[10];const float* lnfb=(const float*)d_in[11];
  const float* posw=(const float*)d_in[12];const float* posb=(const float*)d_in[13];
  const float* lnpg=(const float*)d_in[14];const float* lnpb=(const float*)d_in[15];
  const float* g1w=(const float*)d_in[16]; const float* g1b=(const float*)d_in[17];
  const float* g2w=(const float*)d_in[18]; const float* g2b=(const float*)d_in[19];
  const float* g3w=(const float*)d_in[20]; const float* g3b=(const float*)d_in[21];
  const float* p1w=(const float*)d_in[22]; const float* p1b=(const float*)d_in[23];
  const float* p2w=(const float*)d_in[24]; const float* p2b=(const float*)d_in[25];
  const float* p3w=(const float*)d_in[26]; const float* p3b=(const float*)d_in[27];
  const float* aw1=(const float*)d_in[28]; const float* ab1=(const float*)d_in[29];
  const float* aw2=(const float*)d_in[30]; const float* ab2=(const float*)d_in[31];
  const float* cw =(const float*)d_in[32]; const float* cb =(const float*)d_in[33];
  float* out=(float*)d_out;
  float* W=(float*)d_ws;

  // tiered chunking to fit ws_size (constant across calls -> graph-safe)
  int chunk;
  if      (ws_size >= (size_t)20316416*4) chunk=128;   // 81.3 MB
  else if (ws_size >= (size_t)14583936*4) chunk=64;    // 58.3 MB
  else                                    chunk=32;    // 46.9 MB (best effort)
  const int nch = 512/chunk;
  const int mtn = chunk>=128 ? 2 : 1;
  const int mtshift = chunk>=128 ? 1 : 0;
  const int mrows = chunk<64 ? chunk : 64;

  const size_t A_OFF  = 0;
  const size_t BC_OFF = (size_t)chunk*58320;           // A elems
  const size_t HP_OFF = BC_OFF + (size_t)chunk*31250;  // Bc elems
  const size_t FEAT_OFF = HP_OFF + (size_t)32*512*500;
  const size_t XW_OFF  = FEAT_OFF+262144;
  const size_t Z_OFF   = XW_OFF+131072;
  const size_t XN_OFF  = Z_OFF+131072;
  const size_t INST_OFF= XN_OFF+131072;

  for(int ch=0;ch<nch;++ch){
    k_conv1<<<dim3(24,chunk),256,0,stream>>>(x,c1w,c1b,W+A_OFF,ch*chunk);
    k_conv2<<<dim3(25,chunk),128,0,stream>>>(W+A_OFF,c2w,c2b,W+BC_OFF);
    k_fc<<<dim3(32*mtn*8),256,0,stream>>>(W+BC_OFF,fcw,W+HP_OFF,ch*chunk,mtshift,mrows);
  }
  k_feat<<<dim3(128),256,0,stream>>>(W+HP_OFF,fcb,lnfg,lnfb,info,posw,posb,lnpg,lnpb,W+FEAT_OFF);
  k_xw1<<<dim3(16,8),256,0,stream>>>(W+FEAT_OFF,g1w,W+XW_OFF);
  k_patch<<<dim3(8),1024,0,stream>>>(W+FEAT_OFF,W+XW_OFF,W+Z_OFF,W+XN_OFF,
      g1b,g2w,g2b,g3w,g3b,p1w,p1b,p2w,p2b,p3w,p3b,W+INST_OFF);
  k_final<<<1,256,0,stream>>>(W+INST_OFF,aw1,ab1,aw2,ab2,cw,cb,y,out);
}

// Round 8
// 1989.555 us; speedup vs baseline: 1.6058x; 1.2971x over previous
//
#include <hip/hip_runtime.h>
#include <math.h>

#define EPSV 1e-5f

__device__ __forceinline__ float wsum(float v){
  #pragma unroll
  for(int m=32;m;m>>=1) v += __shfl_xor(v,m);
  return v;
}
__device__ __forceinline__ float wmax_(float v){
  #pragma unroll
  for(int m=32;m;m>>=1) v = fmaxf(v,__shfl_xor(v,m));
  return v;
}

// ------------------------------------------------------------------
// conv1 (3->20, 5x5, VALID) + bias + relu + 2x2 maxpool -> A[np][20][54][54]
// grid (24 = rowt*4 + colh*2 + och, chunk). 256 thr. Compact runtime body
// (R6 lesson: full unroll blew I-cache; batch s_loads ahead of FMA burst).
// ------------------------------------------------------------------
__global__ __launch_bounds__(256,2) void k_conv1(const float* __restrict__ x,
    const float* __restrict__ w, const float* __restrict__ b,
    float* __restrict__ A, int n0){
  const int np = blockIdx.y, bx = blockIdx.x, t = threadIdx.x;
  const int och = bx&1, colh = (bx>>1)&1, rowt = bx>>2;   // rowt in [0,6)
  __shared__ float s_in[3][22][59];
  const float* xb = x + (size_t)(n0+np)*3*112*112;
  const int g0 = rowt*18, c0 = colh*54;
  for(int idx=t; idx<3*22*58; idx+=256){
    int c=idx/(22*58), rem=idx%(22*58), rr=rem/58, cc=rem%58;
    s_in[c][rr][cc]=xb[(size_t)c*12544 + (g0+rr)*112 + c0+cc];
  }
  __syncthreads();
  const int item = t<243 ? t : 242;                       // 9 rows x 27 cols
  const int ly=item/27, ox=item%27;
  float acc[10][4];
  #pragma unroll
  for(int oo=0;oo<10;++oo){acc[oo][0]=0.f;acc[oo][1]=0.f;acc[oo][2]=0.f;acc[oo][3]=0.f;}
  const float* wb_ = w + (och*10)*75;                     // uniform
  #pragma unroll 1
  for(int c=0;c<3;++c){
    const float* sb = &s_in[c][2*ly][2*ox];
    const float* wc = wb_ + c*25;
    #pragma unroll 1
    for(int ky=0;ky<5;++ky){
      float wv[10][5];                                    // uniform vals
      #pragma unroll
      for(int oo=0;oo<10;++oo)
        #pragma unroll
        for(int kx=0;kx<5;++kx) wv[oo][kx]=wc[oo*75+ky*5+kx];
      float ra[6], rb2[6];
      #pragma unroll
      for(int q=0;q<6;++q) ra[q]=sb[ky*59+q];
      #pragma unroll
      for(int q=0;q<6;++q) rb2[q]=sb[(ky+1)*59+q];
      #pragma unroll
      for(int oo=0;oo<10;++oo)
        #pragma unroll
        for(int kx=0;kx<5;++kx){
          float wvv=wv[oo][kx];
          acc[oo][0]=fmaf(wvv,ra[kx],acc[oo][0]);
          acc[oo][1]=fmaf(wvv,ra[kx+1],acc[oo][1]);
          acc[oo][2]=fmaf(wvv,rb2[kx],acc[oo][2]);
          acc[oo][3]=fmaf(wvv,rb2[kx+1],acc[oo][3]);
        }
    }
  }
  if(t<243){
    const int oy=rowt*9+ly, gx=colh*27+ox;
    #pragma unroll
    for(int oo=0;oo<10;++oo){
      const int oc=och*10+oo;
      float m=fmaxf(fmaxf(acc[oo][0],acc[oo][1]),fmaxf(acc[oo][2],acc[oo][3]));
      A[(((size_t)np*20+oc)*54+oy)*54+gx]=fmaxf(m+b[oc],0.f);
    }
  }
}

// ------------------------------------------------------------------
// conv2 (20->50, 5x5) + bias + relu + 2x2 maxpool -> Bc[np][50][25][25]
// grid (25 = rt*5 + ocg, chunk). 128 thr. Same compact-body scheme.
// ------------------------------------------------------------------
__global__ __launch_bounds__(128,2) void k_conv2(const float* __restrict__ A,
    const float* __restrict__ w, const float* __restrict__ b,
    float* __restrict__ Bc){
  const int np = blockIdx.y, bx = blockIdx.x, t = threadIdx.x;
  const int ocg = bx%5, rt = bx/5;
  __shared__ float s_in[4][14][55];
  const int item = t<125 ? t : 124;
  const int ly=item/25, ox=item%25;
  const int r0 = rt*10;
  float acc[10][4];
  #pragma unroll
  for(int oo=0;oo<10;++oo){acc[oo][0]=0.f;acc[oo][1]=0.f;acc[oo][2]=0.f;acc[oo][3]=0.f;}
  #pragma unroll 1
  for(int ch=0; ch<20; ch+=4){
    __syncthreads();
    for(int idx=t; idx<3024; idx+=128){
      int c=idx/756, rem=idx%756, r=rem/54, cc=rem%54;
      s_in[c][r][cc]=A[(((size_t)np*20+ch+c)*54+r0+r)*54+cc];
    }
    __syncthreads();
    #pragma unroll 1
    for(int c=0;c<4;++c){
      const float* sb = &s_in[c][2*ly][2*ox];
      const float* wc = w + ((ocg*10)*20 + ch+c)*25;      // uniform
      #pragma unroll 1
      for(int ky=0;ky<5;++ky){
        float wv[10][5];                                  // uniform vals
        #pragma unroll
        for(int oo=0;oo<10;++oo)
          #pragma unroll
          for(int kx=0;kx<5;++kx) wv[oo][kx]=wc[oo*500+ky*5+kx];
        float ra[6], rb2[6];
        #pragma unroll
        for(int q=0;q<6;++q) ra[q]=sb[ky*55+q];
        #pragma unroll
        for(int q=0;q<6;++q) rb2[q]=sb[(ky+1)*55+q];
        #pragma unroll
        for(int oo=0;oo<10;++oo)
          #pragma unroll
          for(int kx=0;kx<5;++kx){
            float wvv=wv[oo][kx];
            acc[oo][0]=fmaf(wvv,ra[kx],acc[oo][0]);
            acc[oo][1]=fmaf(wvv,ra[kx+1],acc[oo][1]);
            acc[oo][2]=fmaf(wvv,rb2[kx],acc[oo][2]);
            acc[oo][3]=fmaf(wvv,rb2[kx+1],acc[oo][3]);
          }
      }
    }
  }
  if(t<125){
    const int oy=rt*5+ly;
    #pragma unroll
    for(int oo=0;oo<10;++oo){
      const int oc=ocg*10+oo;
      float m=fmaxf(fmaxf(acc[oo][0],acc[oo][1]),fmaxf(acc[oo][2],acc[oo][3]));
      Bc[(((size_t)np*50+oc)*25+oy)*25+ox]=fmaxf(m+b[oc],0.f);
    }
  }
}

// ------------------------------------------------------------------
// fc partials: Hp[ks][m_base+m0+r][n] = X_chunk[m0+r][:] . W[n][:]  (K split 32)
// R7 lesson: scalar-weight streaming = 9.5% VALU (latency-bound). Back to
// both-operands-in-LDS: k-major tiles, inner = 2 ds_read_b128 + 16 FMA.
// grid 8nt*32ks*mtn; 256 thr. nt fastest -> X-tile L2 sharing.
// ------------------------------------------------------------------
__global__ __launch_bounds__(256,2) void k_fc(const float* __restrict__ X,
    const float* __restrict__ Wt, float* __restrict__ Hp, int m_base,
    int mtshift, int mrows){
  (void)mtshift;
  const int bid=blockIdx.x, t=threadIdx.x;
  const int nt=bid&7, ks=(bid>>3)&31, mt=bid>>8;
  const int kbase=ks*1024;
  const int kend=(31250 < kbase+1024) ? 31250 : (kbase+1024);
  const int m0=mt*64, n0=nt*64;
  __shared__ float s_X[64][68];   // k-major: [kk][m]
  __shared__ float s_W[64][68];   // k-major: [kk][n]
  const int msub=t&15, nsub=t>>4;
  float acc[4][4];
  #pragma unroll
  for(int i=0;i<4;++i){acc[i][0]=0.f;acc[i][1]=0.f;acc[i][2]=0.f;acc[i][3]=0.f;}
  for(int kb=kbase; kb<kend; kb+=64){
    __syncthreads();
    const bool full=(kb+64)<=kend;
    #pragma unroll
    for(int s2=0;s2<4;++s2){
      int q=t+256*s2;
      int r=q>>4, k4=(q&15)*4;
      {
        int rc = r<mrows ? r : mrows-1;
        const float* src=X+(size_t)(m0+rc)*31250+kb+k4;
        float v0,v1,v2,v3;
        if(full){ float4 vv=*reinterpret_cast<const float4*>(src); v0=vv.x;v1=vv.y;v2=vv.z;v3=vv.w; }
        else{
          v0=(kb+k4+0<kend)?src[0]:0.f; v1=(kb+k4+1<kend)?src[1]:0.f;
          v2=(kb+k4+2<kend)?src[2]:0.f; v3=(kb+k4+3<kend)?src[3]:0.f;
        }
        s_X[k4][r]=v0; s_X[k4+1][r]=v1; s_X[k4+2][r]=v2; s_X[k4+3][r]=v3;
      }
      {
        int n=n0+r; int nc = n<500 ? n : 499;
        const float* src=Wt+(size_t)nc*31250+kb+k4;
        float v0,v1,v2,v3;
        if(full){ float4 vv=*reinterpret_cast<const float4*>(src); v0=vv.x;v1=vv.y;v2=vv.z;v3=vv.w; }
        else{
          v0=(kb+k4+0<kend)?src[0]:0.f; v1=(kb+k4+1<kend)?src[1]:0.f;
          v2=(kb+k4+2<kend)?src[2]:0.f; v3=(kb+k4+3<kend)?src[3]:0.f;
        }
        s_W[k4][r]=v0; s_W[k4+1][r]=v1; s_W[k4+2][r]=v2; s_W[k4+3][r]=v3;
      }
    }
    __syncthreads();
    #pragma unroll 8
    for(int kk=0;kk<64;++kk){
      float4 xv=*reinterpret_cast<const float4*>(&s_X[kk][msub*4]);
      float4 wv=*reinterpret_cast<const float4*>(&s_W[kk][nsub*4]);
      acc[0][0]=fmaf(xv.x,wv.x,acc[0][0]); acc[0][1]=fmaf(xv.x,wv.y,acc[0][1]);
      acc[0][2]=fmaf(xv.x,wv.z,acc[0][2]); acc[0][3]=fmaf(xv.x,wv.w,acc[0][3]);
      acc[1][0]=fmaf(xv.y,wv.x,acc[1][0]); acc[1][1]=fmaf(xv.y,wv.y,acc[1][1]);
      acc[1][2]=fmaf(xv.y,wv.z,acc[1][2]); acc[1][3]=fmaf(xv.y,wv.w,acc[1][3]);
      acc[2][0]=fmaf(xv.z,wv.x,acc[2][0]); acc[2][1]=fmaf(xv.z,wv.y,acc[2][1]);
      acc[2][2]=fmaf(xv.z,wv.z,acc[2][2]); acc[2][3]=fmaf(xv.z,wv.w,acc[2][3]);
      acc[3][0]=fmaf(xv.w,wv.x,acc[3][0]); acc[3][1]=fmaf(xv.w,wv.y,acc[3][1]);
      acc[3][2]=fmaf(xv.w,wv.z,acc[3][2]); acc[3][3]=fmaf(xv.w,wv.w,acc[3][3]);
    }
  }
  // coalesced store via LDS transpose (reuse s_X as [m][n] staging)
  __syncthreads();
  #pragma unroll
  for(int i=0;i<4;++i){
    float4 vv; vv.x=acc[i][0]; vv.y=acc[i][1]; vv.z=acc[i][2]; vv.w=acc[i][3];
    *reinterpret_cast<float4*>(&s_X[msub*4+i][nsub*4])=vv;
  }
  __syncthreads();
  for(int idx=t; idx<4096; idx+=256){
    int r=idx>>6, c=idx&63, n=n0+c;
    if(r<mrows && n<500) Hp[((size_t)ks*512 + m_base+m0+r)*500+n]=s_X[r][c];
  }
}

// ------------------------------------------------------------------
// feat: relu(sum_ks Hp + fc_b) -> LN(500) | pos: LN(info@posw^T+posb, 12)
// feat[r][0..499]=f, [500..511]=p.  grid 128 x 256 (wave per row)
// ------------------------------------------------------------------
__global__ __launch_bounds__(256) void k_feat(const float* __restrict__ Hp,
    const float* __restrict__ fcb, const float* __restrict__ lnfg, const float* __restrict__ lnfb,
    const float* __restrict__ info, const float* __restrict__ posw, const float* __restrict__ posb,
    const float* __restrict__ lnpg, const float* __restrict__ lnpb, float* __restrict__ feat){
  const int t=threadIdx.x, wave=t>>6, lane=t&63;
  const int r=blockIdx.x*4+wave;
  float v[8];
  #pragma unroll
  for(int q=0;q<8;++q){
    int j=lane+64*q;
    if(j<500){
      float a=fcb[j];
      #pragma unroll
      for(int ks=0;ks<32;++ks) a+=Hp[((size_t)ks*512+r)*500+j];
      v[q]=fmaxf(a,0.f);
    } else v[q]=0.f;
  }
  float s=0.f;
  #pragma unroll
  for(int q=0;q<8;++q) s+=v[q];
  s=wsum(s);
  float mu=s/500.f;
  float ss=0.f;
  #pragma unroll
  for(int q=0;q<8;++q){ int j=lane+64*q; if(j<500){ float d=v[q]-mu; ss+=d*d; } }
  ss=wsum(ss);
  float inv=1.f/sqrtf(ss/500.f+EPSV);
  #pragma unroll
  for(int q=0;q<8;++q){
    int j=lane+64*q;
    if(j<500) feat[(size_t)r*512+j]=(v[q]-mu)*inv*lnfg[j]+lnfb[j];
  }
  if(lane==0){
    float ip[6];
    #pragma unroll
    for(int j=0;j<6;++j) ip[j]=info[r*6+j];
    float qv[12]; float mu2=0.f;
    #pragma unroll
    for(int k=0;k<12;++k){
      float a=posb[k];
      #pragma unroll
      for(int j=0;j<6;++j) a=fmaf(ip[j],posw[k*6+j],a);
      qv[k]=a; mu2+=a;
    }
    mu2*=(1.f/12.f);
    float ss2=0.f;
    #pragma unroll
    for(int k=0;k<12;++k){ float d=qv[k]-mu2; ss2+=d*d; }
    float inv2=1.f/sqrtf(ss2/12.f+EPSV);
    #pragma unroll
    for(int k=0;k<12;++k)
      feat[(size_t)r*512+500+k]=(qv[k]-mu2)*inv2*lnpg[k]+lnpb[k];
  }
}

// ------------------------------------------------------------------
// xw1[i][o] = feat[i,:512] . g1w[o,:512]   (per patch). grid (16 igroups, 8 p)
// ------------------------------------------------------------------
__global__ __launch_bounds__(256) void k_xw1(const float* __restrict__ feat,
    const float* __restrict__ w1, float* __restrict__ xw){
  const int p=blockIdx.y, ig=blockIdx.x, t=threadIdx.x;
  const int o=t;
  __shared__ float s_f[4][512];
  __shared__ float s_w[16][260];
  #pragma unroll
  for(int s2=0;s2<2;++s2){
    int q=t+256*s2; int node=q>>7, c4=(q&127)*4;
    float4 vv=*reinterpret_cast<const float4*>(&feat[((size_t)p*64+ig*4+node)*512+c4]);
    s_f[node][c4]=vv.x; s_f[node][c4+1]=vv.y; s_f[node][c4+2]=vv.z; s_f[node][c4+3]=vv.w;
  }
  float acc[4]={0.f,0.f,0.f,0.f};
  for(int k0=0;k0<512;k0+=16){
    __syncthreads();
    #pragma unroll
    for(int s2=0;s2<4;++s2){
      int qq=t+256*s2; int o2=qq>>2, kk4=(qq&3)*4;
      float4 vv=*reinterpret_cast<const float4*>(&w1[(size_t)o2*512+k0+kk4]);
      s_w[kk4][o2]=vv.x; s_w[kk4+1][o2]=vv.y; s_w[kk4+2][o2]=vv.z; s_w[kk4+3][o2]=vv.w;
    }
    __syncthreads();
    #pragma unroll
    for(int kk=0;kk<16;++kk){
      float wv=s_w[kk][o];
      #pragma unroll
      for(int m=0;m<4;++m) acc[m]=fmaf(s_f[m][k0+kk],wv,acc[m]);
    }
  }
  #pragma unroll
  for(int m=0;m<4;++m) xw[((size_t)p*64+ig*4+m)*256+o]=acc[m];
}

// ------------------------------------------------------------------
// per-patch GCN pipeline (one 1024-thr block per patch)
// ------------------------------------------------------------------
template<int NIN>
__device__ __forceinline__ void gemm_xw(int t, const float* __restrict__ xnp,
    const float* __restrict__ gw, float* __restrict__ xwp, float (*s_chunk)[65]){
  const int o=t&255, ig=t>>8;
  constexpr int IP=NIN/4;
  float acc[IP];
  #pragma unroll
  for(int m=0;m<IP;++m) acc[m]=0.f;
  for(int kc=0;kc<4;++kc){
    __syncthreads();
    if(t<NIN*16){
      int node=t>>4, c4=(t&15)*4;
      float4 vv=*reinterpret_cast<const float4*>(&xnp[(size_t)node*256+kc*64+c4]);
      s_chunk[node][c4]=vv.x; s_chunk[node][c4+1]=vv.y; s_chunk[node][c4+2]=vv.z; s_chunk[node][c4+3]=vv.w;
    }
    __syncthreads();
    const float* gwo = gw + (size_t)o*256 + kc*64;
    #pragma unroll 16
    for(int k=0;k<64;++k){
      float wv=gwo[k];
      #pragma unroll
      for(int m=0;m<IP;++m) acc[m]=fmaf(s_chunk[ig*IP+m][k],wv,acc[m]);
    }
  }
  #pragma unroll
  for(int m=0;m<IP;++m) xwp[(size_t)(ig*IP+m)*256+o]=acc[m];
  __syncthreads();
}

template<int NIN, int NOUT, bool BUILD_NEXT>
__device__ __forceinline__ void stage_body(int t,
    const float* __restrict__ xwp, float* __restrict__ zp, float* __restrict__ xnp,
    const float* __restrict__ gb, const float* __restrict__ pw, const float* __restrict__ pb,
    float (*s_na)[65], float* s_sin, float* s_score, float* s_vals, float* s_gate,
    float* s_dinv, int* s_perm, unsigned long long* s_adj, unsigned long long* s_adjN,
    float* s_res){
  const int lane=t&63, wave=t>>6;
  // combine: z[j][o] = relu(gb[o] + sum_i na[j][i]*xw[i][o])
  {
    const int o=t&255, jg=t>>8;
    constexpr int JP=NIN/4;
    float acc[JP];
    #pragma unroll
    for(int m=0;m<JP;++m) acc[m]=0.f;
    #pragma unroll 4
    for(int i=0;i<NIN;++i){
      float v=xwp[(size_t)i*256+o];
      #pragma unroll
      for(int m=0;m<JP;++m) acc[m]=fmaf(s_na[jg*JP+m][i],v,acc[m]);
    }
    float bo=gb[o];
    #pragma unroll
    for(int m=0;m<JP;++m) zp[(size_t)(jg*JP+m)*256+o]=fmaxf(acc[m]+bo,0.f);
  }
  __syncthreads();
  // scorer input: s_sin[i] = z[i,:] . pw
  for(int i=wave;i<NIN;i+=16){
    float a=0.f;
    #pragma unroll
    for(int q=0;q<4;++q){ int o=lane+64*q; a=fmaf(zp[(size_t)i*256+o],pw[o],a); }
    a=wsum(a);
    if(lane==0) s_sin[i]=a;
  }
  __syncthreads();
  if(t<NIN){
    float a=pb[0];
    for(int i=0;i<NIN;++i) a=fmaf(s_na[t][i],s_sin[i],a);
    s_score[t]=a;
  }
  __syncthreads();
  // top-k (stable descending, tie -> lower index; matches lax.top_k)
  if(t<NIN){
    float my=s_score[t]; int r=0;
    for(int k=0;k<NIN;++k){ float sk=s_score[k]; r += (int)((sk>my)||(sk==my && k<t)); }
    if(r<NOUT){ s_perm[r]=t; s_vals[r]=my; }
  }
  __syncthreads();
  if(t<NOUT) s_gate[t]=tanhf(s_vals[t]);
  __syncthreads();
  // xn[r][o] = z[perm[r]][o] * gate[r]
  {
    const int o=t&255, rg=t>>8;
    constexpr int RP=(NOUT+3)/4;
    #pragma unroll
    for(int m=0;m<RP;++m){
      int r=rg*RP+m;
      if(r<NOUT) xnp[(size_t)r*256+o]=zp[(size_t)s_perm[r]*256+o]*s_gate[r];
    }
  }
  __syncthreads();
  // res += concat(max, mean)
  if(t<256){
    float mx=-1e30f, sm=0.f;
    #pragma unroll 4
    for(int r=0;r<NOUT;++r){ float v=xnp[(size_t)r*256+t]; mx=fmaxf(mx,v); sm+=v; }
    s_res[t]+=mx; s_res[256+t]+=sm/(float)NOUT;
  }
  __syncthreads();
  if constexpr(BUILD_NEXT){
    if(t<NOUT){
      int pr=s_perm[t];
      unsigned long long bits=0ULL;
      unsigned long long rowa=s_adj[pr];
      for(int c=0;c<NOUT;++c)
        bits |= ((rowa>>s_perm[c])&1ULL)<<c;
      s_adjN[t]=bits;
    }
    __syncthreads();
    if(t<NOUT) s_adj[t]=s_adjN[t];
    __syncthreads();
    if(t<NOUT){
      int c=1;
      for(int i=0;i<NOUT;++i) c+=(int)((s_adj[i]>>t)&1ULL);
      s_dinv[t]=1.f/sqrtf((float)c);
    }
    __syncthreads();
    for(int q=t;q<NOUT*NOUT;q+=1024){
      int i=q/NOUT, j=q%NOUT;
      float cv=0.f;
      if(i==j || ((s_adj[i]>>j)&1ULL)) cv=s_dinv[i]*s_dinv[j];
      s_na[j][i]=cv;
    }
    __syncthreads();
  }
}

__global__ __launch_bounds__(1024) void k_patch(
    const float* __restrict__ feat, float* __restrict__ xwb,
    float* __restrict__ zb, float* __restrict__ xnb,
    const float* __restrict__ g1b,
    const float* __restrict__ g2w, const float* __restrict__ g2b,
    const float* __restrict__ g3w, const float* __restrict__ g3b,
    const float* __restrict__ p1w, const float* __restrict__ p1b,
    const float* __restrict__ p2w, const float* __restrict__ p2b,
    const float* __restrict__ p3w, const float* __restrict__ p3b,
    float* __restrict__ inst){
  const int p=blockIdx.x, t=threadIdx.x, lane=t&63, wave=t>>6;
  __shared__ float s_G[64][65];
  __shared__ float s_na[64][65];
  __shared__ float s_chunk[64][65];
  __shared__ float s_sin[64], s_score[64], s_vals[64], s_gate[64], s_dinv[64];
  __shared__ int s_perm[64];
  __shared__ unsigned long long s_adj[64], s_adjN[64];
  __shared__ float s_res[512];
  __shared__ float s_red[16];
  __shared__ float s_thr;

  const float* featp = feat + (size_t)p*64*512;
  float* xwp = xwb + (size_t)p*64*256;
  float* zp  = zb  + (size_t)p*64*256;
  float* xnp = xnb + (size_t)p*64*256;

  if(t<512) s_res[t]=0.f;

  // Gram matrix (64x64, K=512) via LDS chunks
  float gacc[4]={0.f,0.f,0.f,0.f};
  for(int kc=0;kc<8;++kc){
    __syncthreads();
    {
      int node=t>>4, c4=(t&15)*4;
      float4 vv=*reinterpret_cast<const float4*>(&featp[(size_t)node*512+kc*64+c4]);
      s_chunk[node][c4]=vv.x; s_chunk[node][c4+1]=vv.y; s_chunk[node][c4+2]=vv.z; s_chunk[node][c4+3]=vv.w;
    }
    __syncthreads();
    #pragma unroll
    for(int m=0;m<4;++m){
      int i=wave+16*m;
      float a=0.f;
      #pragma unroll 8
      for(int k=0;k<64;++k) a=fmaf(s_chunk[i][k],s_chunk[lane][k],a);
      gacc[m]+=a;
    }
  }
  __syncthreads();
  #pragma unroll
  for(int m=0;m<4;++m) s_G[wave+16*m][lane]=gacc[m];
  __syncthreads();
  // max pairwise sq-distance
  {
    float mx=-1e30f;
    #pragma unroll
    for(int m=0;m<4;++m){
      int i=wave+16*m;
      float d=s_G[i][i]+s_G[lane][lane]-2.f*s_G[i][lane];
      mx=fmaxf(mx,d);
    }
    mx=wmax_(mx);
    if(lane==0) s_red[wave]=mx;
  }
  __syncthreads();
  if(t==0){
    float mx=s_red[0];
    for(int i=1;i<16;++i) mx=fmaxf(mx,s_red[i]);
    s_thr=0.5f*mx;          // T = 0.5
  }
  __syncthreads();
  // adjacency bits (strict upper triangle, dist < thr strict)
  if(t<64){
    unsigned long long bits=0ULL;
    float thr=s_thr, gii=s_G[t][t];
    for(int j=t+1;j<64;++j){
      float d=gii+s_G[j][j]-2.f*s_G[t][j];
      if(d<thr) bits|=(1ULL<<j);
    }
    s_adj[t]=bits;
  }
  __syncthreads();
  if(t<64){
    int c=1;
    for(int i=0;i<64;++i) c+=(int)((s_adj[i]>>t)&1ULL);
    s_dinv[t]=1.f/sqrtf((float)c);
  }
  __syncthreads();
  for(int q=t;q<64*64;q+=1024){
    int i=q>>6, j=q&63;
    float cv=0.f;
    if(i==j || ((s_adj[i]>>j)&1ULL)) cv=s_dinv[i]*s_dinv[j];
    s_na[j][i]=cv;
  }
  __syncthreads();

  stage_body<64,48,true >(t,xwp,zp,xnp,g1b,p1w,p1b,s_na,s_sin,s_score,s_vals,s_gate,s_dinv,s_perm,s_adj,s_adjN,s_res);
  gemm_xw<48>(t,xnp,g2w,xwp,s_chunk);
  stage_body<48,36,true >(t,xwp,zp,xnp,g2b,p2w,p2b,s_na,s_sin,s_score,s_vals,s_gate,s_dinv,s_perm,s_adj,s_adjN,s_res);
  gemm_xw<36>(t,xnp,g3w,xwp,s_chunk);
  stage_body<36,27,false>(t,xwp,zp,xnp,g3b,p3w,p3b,s_na,s_sin,s_score,s_vals,s_gate,s_dinv,s_perm,s_adj,s_adjN,s_res);

  if(t<512) inst[(size_t)p*512+t]=s_res[t];
}

// ------------------------------------------------------------------
// attention MIL head + classifier + outputs (1 block)
// ------------------------------------------------------------------
__global__ __launch_bounds__(256) void k_final(
    const float* __restrict__ inst, const float* __restrict__ aw1, const float* __restrict__ ab1,
    const float* __restrict__ aw2, const float* __restrict__ ab2,
    const float* __restrict__ cw, const float* __restrict__ cb,
    const float* __restrict__ y, float* __restrict__ out){
  const int t=threadIdx.x;
  __shared__ float s_inst[8][512];
  __shared__ float s_t1[8][128];
  __shared__ float s_a[8];
  __shared__ float s_aw[8];
  __shared__ float s_bag[512];
  for(int q=t;q<4096;q+=256) s_inst[q>>9][q&511]=inst[q];
  __syncthreads();
  for(int q=t;q<1024;q+=256){
    int pp=q>>7, k=q&127;
    float a=ab1[k];
    for(int o=0;o<512;++o) a=fmaf(s_inst[pp][o],aw1[(size_t)k*512+o],a);
    s_t1[pp][k]=tanhf(a);
  }
  __syncthreads();
  if(t<8){
    float a=ab2[0];
    for(int k=0;k<128;++k) a=fmaf(s_t1[t][k],aw2[k],a);
    s_a[t]=a;
  }
  __syncthreads();
  if(t==0){
    float m=s_a[0];
    for(int i=1;i<8;++i) m=fmaxf(m,s_a[i]);
    float e[8]; float sm=0.f;
    for(int i=0;i<8;++i){ e[i]=expf(s_a[i]-m); sm+=e[i]; }
    for(int i=0;i<8;++i){ s_aw[i]=e[i]/sm; out[3+i]=s_aw[i]; }
  }
  __syncthreads();
  for(int o=t;o<512;o+=256){
    float a=0.f;
    #pragma unroll
    for(int pp=0;pp<8;++pp) a=fmaf(s_aw[pp],s_inst[pp][o],a);
    s_bag[o]=a;
  }
  __syncthreads();
  if(t<64){
    float a=0.f;
    #pragma unroll
    for(int q=0;q<8;++q){ int o=t+64*q; a=fmaf(s_bag[o],cw[o],a); }
    a=wsum(a);
    if(t==0){
      float logit=a+cb[0];
      float prob=1.f/(1.f+expf(-logit));
      float pc=fminf(fmaxf(prob,1e-5f),1.f-1e-5f);
      float pred=(prob>=0.5f)?1.f:0.f;
      float yy=y[0];
      float loss=-(yy*logf(pc)+(1.f-yy)*logf(1.f-pc));
      out[0]=pc; out[1]=pred; out[2]=loss;
    }
  }
}

// ------------------------------------------------------------------
extern "C" void kernel_launch(void* const* d_in, const int* in_sizes, int n_in,
                              void* d_out, int out_size, void* d_ws, size_t ws_size,
                              hipStream_t stream){
  (void)in_sizes; (void)n_in; (void)out_size;
  const float* x   =(const float*)d_in[0];
  const float* info=(const float*)d_in[1];
  const float* y   =(const float*)d_in[2];
  const float* c1w=(const float*)d_in[4];  const float* c1b=(const float*)d_in[5];
  const float* c2w=(const float*)d_in[6];  const float* c2b=(const float*)d_in[7];
  const float* fcw=(const float*)d_in[8];  const float* fcb=(const float*)d_in[9];
  const float* lnfg=(const float*)d_in[10];const float* lnfb=(const float*)d_in[11];
  const float* posw=(const float*)d_in[12];const float* posb=(const float*)d_in[13];
  const float* lnpg=(const float*)d_in[14];const float* lnpb=(const float*)d_in[15];
  const float* g1w=(const float*)d_in[16]; const float* g1b=(const float*)d_in[17];
  const float* g2w=(const float*)d_in[18]; const float* g2b=(const float*)d_in[19];
  const float* g3w=(const float*)d_in[20]; const float* g3b=(const float*)d_in[21];
  const float* p1w=(const float*)d_in[22]; const float* p1b=(const float*)d_in[23];
  const float* p2w=(const float*)d_in[24]; const float* p2b=(const float*)d_in[25];
  const float* p3w=(const float*)d_in[26]; const float* p3b=(const float*)d_in[27];
  const float* aw1=(const float*)d_in[28]; const float* ab1=(const float*)d_in[29];
  const float* aw2=(const float*)d_in[30]; const float* ab2=(const float*)d_in[31];
  const float* cw =(const float*)d_in[32]; const float* cb =(const float*)d_in[33];
  float* out=(float*)d_out;
  float* W=(float*)d_ws;

  // tiered chunking to fit ws_size (constant across calls -> graph-safe)
  int chunk;
  if      (ws_size >= (size_t)20316416*4) chunk=128;   // 81.3 MB
  else if (ws_size >= (size_t)14583936*4) chunk=64;    // 58.3 MB
  else                                    chunk=32;    // 46.9 MB (best effort)
  const int nch = 512/chunk;
  const int mtn = chunk>=128 ? 2 : 1;
  const int mtshift = chunk>=128 ? 1 : 0;
  const int mrows = chunk<64 ? chunk : 64;

  const size_t A_OFF  = 0;
  const size_t BC_OFF = (size_t)chunk*58320;           // A elems
  const size_t HP_OFF = BC_OFF + (size_t)chunk*31250;  // Bc elems
  const size_t FEAT_OFF = HP_OFF + (size_t)32*512*500;
  const size_t XW_OFF  = FEAT_OFF+262144;
  const size_t Z_OFF   = XW_OFF+131072;
  const size_t XN_OFF  = Z_OFF+131072;
  const size_t INST_OFF= XN_OFF+131072;

  for(int ch=0;ch<nch;++ch){
    k_conv1<<<dim3(24,chunk),256,0,stream>>>(x,c1w,c1b,W+A_OFF,ch*chunk);
    k_conv2<<<dim3(25,chunk),128,0,stream>>>(W+A_OFF,c2w,c2b,W+BC_OFF);
    k_fc<<<dim3(8*32*mtn),256,0,stream>>>(W+BC_OFF,fcw,W+HP_OFF,ch*chunk,mtshift,mrows);
  }
  k_feat<<<dim3(128),256,0,stream>>>(W+HP_OFF,fcb,lnfg,lnfb,info,posw,posb,lnpg,lnpb,W+FEAT_OFF);
  k_xw1<<<dim3(16,8),256,0,stream>>>(W+FEAT_OFF,g1w,W+XW_OFF);
  k_patch<<<dim3(8),1024,0,stream>>>(W+FEAT_OFF,W+XW_OFF,W+Z_OFF,W+XN_OFF,
      g1b,g2w,g2b,g3w,g3b,p1w,p1b,p2w,p2b,p3w,p3b,W+INST_OFF);
  k_final<<<1,256,0,stream>>>(W+INST_OFF,aw1,ab1,aw2,ab2,cw,cb,y,out);
}